// Round 6
// baseline (9701.031 us; speedup 1.0000x reference)
//
#include <hip/hip_runtime.h>
#include <hip/hip_bf16.h>
#include <math.h>

// Problem sizes
#define Bz   512
#define Tz   128
#define INz  64
#define Hz   512
#define TSz  32
#define PLz  32
#define BH   (Bz * Hz)          // 262144
#define NBLK 256
#define PF   4

typedef unsigned short u16;
typedef __attribute__((ext_vector_type(8)))  short short8;
typedef __attribute__((ext_vector_type(16))) float floatx16;

static __device__ __forceinline__ void split_bf(float w, u16& hi, u16& lo) {
    __hip_bfloat16 h = __float2bfloat16(w);
    hi = *reinterpret_cast<u16*>(&h);
    float r = w - __bfloat162float(h);
    __hip_bfloat16 l = __float2bfloat16(r);
    lo = *reinterpret_cast<u16*>(&l);
}

// ---------------- init: zero c, h fragments, sync counters ----------------
__global__ __launch_bounds__(256) void k_init(float* __restrict__ c,
                                              u16* __restrict__ hf_hi,
                                              u16* __restrict__ hf_lo,
                                              unsigned* __restrict__ sync) {
    const int i = blockIdx.x * 256 + threadIdx.x;
    if (i < BH) { c[i] = 0.f; hf_hi[i] = 0; hf_lo[i] = 0; }
    if (i < 16) sync[i] = 0;
}

// ---------------- prep kernels ----------------
__global__ __launch_bounds__(256) void k_prep_wenc(const float* __restrict__ W_ih,
                                                   const float* __restrict__ W_hh,
                                                   u16* __restrict__ wf_hi,
                                                   u16* __restrict__ wf_lo) {
    const int idx = blockIdx.x * 256 + threadIdx.x;
    const int lane = idx & 63;
    const int g = (idx >> 6) % 36;
    const int cb = idx / (36 * 64);
    const int C = cb * 32 + (lane & 31);
    const int gate = ((C >> 4) & 3) * 512 + (C >> 6) * 16 + (C & 15);
    const int kh = lane >> 5;
    const size_t base = (size_t)idx * 8;
    #pragma unroll
    for (int e = 0; e < 8; ++e) {
        const int k = g * 16 + kh * 8 + e;
        const float w = (k < 64) ? W_ih[(size_t)gate * 64 + k]
                                 : W_hh[(size_t)gate * 512 + (k - 64)];
        u16 hi, lo; split_bf(w, hi, lo);
        wf_hi[base + e] = hi; wf_lo[base + e] = lo;
    }
}

__global__ __launch_bounds__(256) void k_prep_wc(const float* __restrict__ Wc_ih,
                                                 const float* __restrict__ Wc_hh,
                                                 u16* __restrict__ wf_hi,
                                                 u16* __restrict__ wf_lo) {
    const int idx = blockIdx.x * 256 + threadIdx.x;
    const int lane = idx & 63;
    const int cb = idx / (32 * 64);
    const int g = (idx >> 6) % 32;
    const int C = cb * 32 + (lane & 31);
    const int gate = ((C >> 4) & 3) * 512 + (C >> 6) * 16 + (C & 15);
    const int kh = lane >> 5;
    const size_t base = (size_t)idx * 8;
    #pragma unroll
    for (int e = 0; e < 8; ++e) {
        const int k = g * 16 + kh * 8 + e;
        const float w = Wc_ih[(size_t)gate * 512 + k] + Wc_hh[(size_t)gate * 512 + k];
        u16 hi, lo; split_bf(w, hi, lo);
        wf_hi[base + e] = hi; wf_lo[base + e] = lo;
    }
}

__global__ __launch_bounds__(256) void k_prep_w1(const float* __restrict__ W1,
                                                 u16* __restrict__ wf_hi,
                                                 u16* __restrict__ wf_lo) {
    const int idx = blockIdx.x * 256 + threadIdx.x;
    const int lane = idx & 63;
    const int cb = idx / (64 * 64);
    const int g = (idx >> 6) % 64;
    const int n = cb * 32 + (lane & 31);
    const int kh = lane >> 5;
    const size_t base = (size_t)idx * 8;
    #pragma unroll
    for (int e = 0; e < 8; ++e) {
        const int k = g * 16 + kh * 8 + e;
        const float w = W1[(size_t)n * 1024 + k];
        u16 hi, lo; split_bf(w, hi, lo);
        wf_hi[base + e] = hi; wf_lo[base + e] = lo;
    }
}

__global__ __launch_bounds__(256) void k_prep_x(const float* __restrict__ x,
                                                u16* __restrict__ xf_hi,
                                                u16* __restrict__ xf_lo) {
    const int idx = blockIdx.x * 256 + threadIdx.x;
    const int lane = idx & 63;
    const int g = (idx >> 6) & 3;
    const int rb = (idx >> 8) & 15;
    const int t = idx >> 12;
    const int b = rb * 32 + (lane & 31);
    const int kh = lane >> 5;
    const size_t base = (size_t)idx * 8;
    #pragma unroll
    for (int e = 0; e < 8; ++e) {
        const int i = g * 16 + kh * 8 + e;
        const float w = x[((size_t)b * Tz + t) * INz + i];
        u16 hi, lo; split_bf(w, hi, lo);
        xf_hi[base + e] = hi; xf_lo[base + e] = lo;
    }
}

// ---------------- grid barrier (agent-scope atomics; relaxed spin) ----------------
__device__ __forceinline__ void gsync(unsigned* sync) {
    __syncthreads();
    if (threadIdx.x == 0) {
        const unsigned g = __hip_atomic_load(&sync[1], __ATOMIC_RELAXED, __HIP_MEMORY_SCOPE_AGENT);
        const unsigned old = __hip_atomic_fetch_add(&sync[0], 1u, __ATOMIC_ACQ_REL, __HIP_MEMORY_SCOPE_AGENT);
        if (old == NBLK - 1) {
            __hip_atomic_store(&sync[0], 0u, __ATOMIC_RELAXED, __HIP_MEMORY_SCOPE_AGENT);
            __hip_atomic_fetch_add(&sync[1], 1u, __ATOMIC_ACQ_REL, __HIP_MEMORY_SCOPE_AGENT);
        } else {
            while (__hip_atomic_load(&sync[1], __ATOMIC_RELAXED, __HIP_MEMORY_SCOPE_AGENT) == g)
                __builtin_amdgcn_s_sleep(2);
            __builtin_amdgcn_fence(__ATOMIC_ACQUIRE, "agent");   // invalidate after release observed
        }
    }
    __syncthreads();
}

// ---------------- gates + cell phase ----------------
template<int NG, int GX>
__device__ __forceinline__ void gates_phase(
    const u16* __restrict__ xf_hi, const u16* __restrict__ xf_lo, int t,
    const u16* __restrict__ wf_hi, const u16* __restrict__ wf_lo,
    const u16* __restrict__ hin_hi, const u16* __restrict__ hin_lo,
    const float* __restrict__ bias,
    float* __restrict__ c, float* __restrict__ h_f32,
    u16* __restrict__ hout_hi, u16* __restrict__ hout_lo,
    float* __restrict__ buf, int slot,
    float* Gt, int bid, int tid)
{
    const int lane = tid & 63, wid = tid >> 6;
    const int wr = wid >> 1, wc = wid & 1;
    const int ji = bid & 31, bi = bid >> 5;
    const int rbIdx = bi * 2 + wr;
    const int cbIdx = ji * 2 + wc;

    floatx16 acc0, acc1, acc2;
    #pragma unroll
    for (int i = 0; i < 16; ++i) { acc0[i] = 0.f; acc1[i] = 0.f; acc2[i] = 0.f; }

    const u16* pb_hi = wf_hi + ((size_t)cbIdx * NG) * 512 + lane * 8;
    const u16* pb_lo = wf_lo + ((size_t)cbIdx * NG) * 512 + lane * 8;

    short8 ah[PF], al[PF], bh[PF], bl[PF];

    #pragma unroll
    for (int g = 0; g < NG + PF; ++g) {
        if (g >= PF) {   // consume granule g-PF
            const int s = (g - PF) & (PF - 1);
            acc0 = __builtin_amdgcn_mfma_f32_32x32x16_bf16(ah[s], bh[s], acc0, 0, 0, 0);
            acc1 = __builtin_amdgcn_mfma_f32_32x32x16_bf16(ah[s], bl[s], acc1, 0, 0, 0);
            acc2 = __builtin_amdgcn_mfma_f32_32x32x16_bf16(al[s], bh[s], acc2, 0, 0, 0);
        }
        if (g < NG) {    // refill with granule g
            const int s = g & (PF - 1);
            const u16* pa_hi;
            const u16* pa_lo;
            if (g < GX) {
                const size_t off = ((((size_t)t * 16 + rbIdx) * 4 + g) * 64 + lane) * 8;
                pa_hi = xf_hi + off; pa_lo = xf_lo + off;
            } else {
                const size_t off = (((size_t)rbIdx * 32 + (g - GX)) * 64 + lane) * 8;
                pa_hi = hin_hi + off; pa_lo = hin_lo + off;
            }
            ah[s] = *(const short8*)pa_hi;
            al[s] = *(const short8*)pa_lo;
            bh[s] = *(const short8*)(pb_hi + (size_t)g * 512);
            bl[s] = *(const short8*)(pb_lo + (size_t)g * 512);
        }
    }
    #pragma unroll
    for (int i = 0; i < 16; ++i) acc0[i] += acc1[i] + acc2[i];

    {   // dump 32x32 frags to Gt[64][64]
        const int col = wc * 32 + (lane & 31);
        const int rbase = wr * 32 + 4 * (lane >> 5);
        #pragma unroll
        for (int r = 0; r < 16; ++r)
            Gt[(rbase + (r & 3) + 8 * (r >> 2)) * 64 + col] = acc0[r];
    }
    __syncthreads();

    // cell update: 64 b x 16 jj
    #pragma unroll
    for (int rr = 0; rr < 4; ++rr) {
        const int idx = rr * 256 + tid;
        const int bl2 = idx >> 4, jj = idx & 15;
        const int b = bi * 64 + bl2;
        const int j = ji * 16 + jj;
        const float gi = Gt[bl2 * 64 + jj]       + bias[j];
        const float gf = Gt[bl2 * 64 + 16 + jj]  + bias[512 + j];
        const float gg = Gt[bl2 * 64 + 32 + jj]  + bias[1024 + j];
        const float go = Gt[bl2 * 64 + 48 + jj]  + bias[1536 + j];
        const float si = 1.f / (1.f + __expf(-gi));
        const float sf = 1.f / (1.f + __expf(-gf));
        const float so = 1.f / (1.f + __expf(-go));
        const size_t o = (size_t)b * Hz + j;
        const float cn = sf * c[o] + si * tanhf(gg);
        const float hn = so * tanhf(cn);
        c[o] = cn;
        if (slot >= 0) buf[((size_t)b * TSz + slot) * Hz + j] = hn;
        else           h_f32[o] = hn;
        u16 hi, lo; split_bf(hn, hi, lo);
        const int rb = b >> 5, gran = j >> 4;
        const int fl = ((j >> 3) & 1) * 32 + (b & 31);
        const size_t fo = (((size_t)rb * 32 + gran) * 64 + fl) * 8 + (j & 7);
        hout_hi[fo] = hi; hout_lo[fo] = lo;
    }
}

// ---------------- attention phase: 2 batches per block, 128 threads each ----------------
__device__ __forceinline__ void attn_phase(const float* __restrict__ h_f32,
                                           float* __restrict__ buf,
                                           u16* __restrict__ ctx_hi, u16* __restrict__ ctx_lo,
                                           int base, float* lds, int bid, int tid) {
    float* sh = lds + (tid >> 7) * 544;
    float* sa = sh + 512;
    const int b = bid * 2 + (tid >> 7);
    const int t7 = tid & 127;
    for (int i = t7; i < 512; i += 128) sh[i] = h_f32[(size_t)b * Hz + i];
    __syncthreads();
    {   // 32 scores, 4 lanes each
        const int s = t7 >> 2, l4 = t7 & 3;
        const float* br = buf + ((size_t)b * TSz + ((base + s) & 31)) * Hz;
        float p = 0.f;
        for (int j = l4; j < 512; j += 4) p = fmaf(sh[j], br[j], p);
        p += __shfl_xor(p, 1); p += __shfl_xor(p, 2);
        if (l4 == 0) sa[s] = p;
    }
    __syncthreads();
    if (t7 < 32) {   // softmax over 32
        const float v = sa[t7];
        float m = v;
        #pragma unroll
        for (int d = 1; d < 32; d <<= 1) m = fmaxf(m, __shfl_xor(m, d));
        const float e = __expf(v - m);
        float ss = e;
        #pragma unroll
        for (int d = 1; d < 32; d <<= 1) ss += __shfl_xor(ss, d);
        sa[t7] = e / ss;
    }
    __syncthreads();
    for (int j = t7; j < 512; j += 128) {
        float a = 0.f;
        #pragma unroll
        for (int s2 = 0; s2 < TSz; ++s2)
            a = fmaf(sa[s2], buf[((size_t)b * TSz + ((base + s2) & 31)) * Hz + j], a);
        u16 hi, lo; split_bf(a, hi, lo);
        const int rb = b >> 5, gran = j >> 4;
        const int fl = ((j >> 3) & 1) * 32 + (b & 31);
        const size_t fo = (((size_t)rb * 32 + gran) * 64 + fl) * 8 + (j & 7);
        ctx_hi[fo] = hi; ctx_lo[fo] = lo;
    }
    __syncthreads();
    for (int i = t7; i < 512; i += 128) buf[((size_t)b * TSz + base) * Hz + i] = sh[i];
}

// ---------------- MLP + partial out phase ----------------
__device__ __forceinline__ void mlp_phase(
    const u16* __restrict__ ctx_hi, const u16* __restrict__ ctx_lo,
    const u16* __restrict__ h_hi,   const u16* __restrict__ h_lo,
    const u16* __restrict__ w1_hi,  const u16* __restrict__ w1_lo,
    const float* __restrict__ b1, const float* __restrict__ W2,
    float* __restrict__ part_p, float* lds, int bid, int tid)
{
    const int lane = tid & 63, w = tid >> 6;
    const int ni = bid & 15, bi2 = bid >> 4;

    floatx16 acc0, acc1, acc2;
    #pragma unroll
    for (int i = 0; i < 16; ++i) { acc0[i] = 0.f; acc1[i] = 0.f; acc2[i] = 0.f; }

    short8 ah[PF], al[PF], bh[PF], bl[PF];

    #pragma unroll
    for (int gg = 0; gg < 16 + PF; ++gg) {
        if (gg >= PF) {
            const int s = (gg - PF) & (PF - 1);
            acc0 = __builtin_amdgcn_mfma_f32_32x32x16_bf16(ah[s], bh[s], acc0, 0, 0, 0);
            acc1 = __builtin_amdgcn_mfma_f32_32x32x16_bf16(ah[s], bl[s], acc1, 0, 0, 0);
            acc2 = __builtin_amdgcn_mfma_f32_32x32x16_bf16(al[s], bh[s], acc2, 0, 0, 0);
        }
        if (gg < 16) {
            const int s = gg & (PF - 1);
            const int g = w * 16 + gg;   // [0,64) K-granule; wave-split K
            const u16* pa_hi;
            const u16* pa_lo;
            if (g < 32) {
                const size_t off = (((size_t)bi2 * 32 + g) * 64 + lane) * 8;
                pa_hi = ctx_hi + off; pa_lo = ctx_lo + off;
            } else {
                const size_t off = (((size_t)bi2 * 32 + (g - 32)) * 64 + lane) * 8;
                pa_hi = h_hi + off; pa_lo = h_lo + off;
            }
            const size_t boff = (((size_t)ni * 64 + g) * 64 + lane) * 8;
            ah[s] = *(const short8*)pa_hi;
            al[s] = *(const short8*)pa_lo;
            bh[s] = *(const short8*)(w1_hi + boff);
            bl[s] = *(const short8*)(w1_lo + boff);
        }
    }
    #pragma unroll
    for (int i = 0; i < 16; ++i) acc0[i] += acc1[i] + acc2[i];

    {   // per-wave 32x32 partial -> lds[w][row][col]
        const int col = lane & 31;
        const int rb4 = 4 * (lane >> 5);
        #pragma unroll
        for (int r = 0; r < 16; ++r)
            lds[w * 1024 + (rb4 + (r & 3) + 8 * (r >> 2)) * 32 + col] = acc0[r];
    }
    __syncthreads();

    // reduce 4 wave-partials + bias, tanh, dot with W2 slice -> part_p[ni][b]
    const int row = tid >> 3, l8 = tid & 7;
    float a = 0.f;
    #pragma unroll
    for (int jj = 0; jj < 4; ++jj) {
        const int col = l8 * 4 + jj;
        const int ncol = ni * 32 + col;
        const float pre = lds[row * 32 + col] + lds[1024 + row * 32 + col]
                        + lds[2048 + row * 32 + col] + lds[3072 + row * 32 + col] + b1[ncol];
        a = fmaf(tanhf(pre), W2[ncol], a);
    }
    a += __shfl_xor(a, 1); a += __shfl_xor(a, 2); a += __shfl_xor(a, 4);
    if (l8 == 0) part_p[ni * 512 + bi2 * 32 + row] = a;
}

__device__ __forceinline__ void y_reduce(const float* __restrict__ part_p,
                                         const float* __restrict__ b2,
                                         float* __restrict__ y, int s, int bid, int tid) {
    if (tid < 2) {
        const int b = bid * 2 + tid;
        float a = b2[0];
        #pragma unroll
        for (int ni = 0; ni < 16; ++ni) a += part_p[ni * 512 + b];
        y[(size_t)b * PLz + s] = a;
    }
}

// ---------------- the persistent kernel (REGULAR launch; 256 blocks <= capacity) ----------------
struct KParams {
    const u16 *xf_hi, *xf_lo, *wf_hi, *wf_lo, *wcf_hi, *wcf_lo, *w1f_hi, *w1f_lo;
    const float *b_l, *b_c, *b1, *W2, *b2;
    float *c, *h_f32, *buf, *part_p, *y;
    u16 *hfa_hi, *hfa_lo, *hfb_hi, *hfb_lo, *ctx_hi, *ctx_lo;
    unsigned *sync;
};

__global__ __launch_bounds__(256) void k_persist(KParams p) {
    __shared__ float lds[4160];
    const int bid = blockIdx.x;
    const int tid = threadIdx.x;

    // encoder: 128 steps
    for (int t = 0; t < Tz; ++t) {
        const u16* in_hi = (t & 1) ? p.hfb_hi : p.hfa_hi;
        const u16* in_lo = (t & 1) ? p.hfb_lo : p.hfa_lo;
        u16* out_hi = (t & 1) ? p.hfa_hi : p.hfb_hi;
        u16* out_lo = (t & 1) ? p.hfa_lo : p.hfb_lo;
        gates_phase<36, 4>(p.xf_hi, p.xf_lo, t, p.wf_hi, p.wf_lo, in_hi, in_lo,
                           p.b_l, p.c, nullptr, out_hi, out_lo, p.buf, t & 31,
                           lds, bid, tid);
        gsync(p.sync);
    }
    // decoder: 32 iterations (gates | attn | mlp+out), 3 barriers each
    for (int s = 0; s < PLz; ++s) {
        if (s > 0) y_reduce(p.part_p, p.b2, p.y, s - 1, bid, tid);
        const u16* in_hi = (s & 1) ? p.hfb_hi : p.hfa_hi;
        const u16* in_lo = (s & 1) ? p.hfb_lo : p.hfa_lo;
        u16* out_hi = (s & 1) ? p.hfa_hi : p.hfb_hi;
        u16* out_lo = (s & 1) ? p.hfa_lo : p.hfb_lo;
        gates_phase<32, 0>(nullptr, nullptr, 0, p.wcf_hi, p.wcf_lo, in_hi, in_lo,
                           p.b_c, p.c, p.h_f32, out_hi, out_lo, nullptr, -1,
                           lds, bid, tid);
        gsync(p.sync);
        attn_phase(p.h_f32, p.buf, p.ctx_hi, p.ctx_lo, s & 31, lds, bid, tid);
        gsync(p.sync);
        mlp_phase(p.ctx_hi, p.ctx_lo, out_hi, out_lo, p.w1f_hi, p.w1f_lo,
                  p.b1, p.W2, p.part_p, lds, bid, tid);
        gsync(p.sync);
    }
    y_reduce(p.part_p, p.b2, p.y, PLz - 1, bid, tid);
}

extern "C" void kernel_launch(void* const* d_in, const int* in_sizes, int n_in,
                              void* d_out, int out_size, void* d_ws, size_t ws_size,
                              hipStream_t stream) {
    (void)in_sizes; (void)n_in; (void)out_size; (void)ws_size;
    const float* x     = (const float*)d_in[0];
    const float* W_ih  = (const float*)d_in[1];
    const float* W_hh  = (const float*)d_in[2];
    const float* b_l   = (const float*)d_in[3];
    const float* Wc_ih = (const float*)d_in[4];
    const float* Wc_hh = (const float*)d_in[5];
    const float* b_c   = (const float*)d_in[6];
    const float* W1    = (const float*)d_in[7];
    const float* b1    = (const float*)d_in[8];
    const float* W2    = (const float*)d_in[9];
    const float* b2    = (const float*)d_in[10];
    float* y = (float*)d_out;

    float* w = (float*)d_ws;
    float* c      = w;                          // BH
    float* h_f32  = w + BH;                     // BH
    float* buf    = w + 2 * (size_t)BH;         // 32*BH
    float* part_p = w + 34 * (size_t)BH;        // 8192
    unsigned* sync = (unsigned*)(w + 34 * (size_t)BH + 8192);   // 16
    u16* us = (u16*)(w + 34 * (size_t)BH + 8192 + 64);
    u16* hfa_hi = us;  us += BH;
    u16* hfa_lo = us;  us += BH;
    u16* hfb_hi = us;  us += BH;
    u16* hfb_lo = us;  us += BH;
    u16* ctx_hi = us;  us += BH;
    u16* ctx_lo = us;  us += BH;
    u16* xf_hi = us;   us += 4194304;
    u16* xf_lo = us;   us += 4194304;
    u16* wf_hi = us;   us += 1179648;
    u16* wf_lo = us;   us += 1179648;
    u16* wcf_hi = us;  us += 1048576;
    u16* wcf_lo = us;  us += 1048576;
    u16* w1f_hi = us;  us += 524288;
    u16* w1f_lo = us;  us += 524288;

    k_init     <<<1024, 256, 0, stream>>>(c, hfa_hi, hfa_lo, sync);
    k_prep_wenc<<<576,  256, 0, stream>>>(W_ih, W_hh, wf_hi, wf_lo);
    k_prep_wc  <<<512,  256, 0, stream>>>(Wc_ih, Wc_hh, wcf_hi, wcf_lo);
    k_prep_w1  <<<256,  256, 0, stream>>>(W1, w1f_hi, w1f_lo);
    k_prep_x   <<<2048, 256, 0, stream>>>(x, xf_hi, xf_lo);

    KParams prm;
    prm.xf_hi = xf_hi;   prm.xf_lo = xf_lo;
    prm.wf_hi = wf_hi;   prm.wf_lo = wf_lo;
    prm.wcf_hi = wcf_hi; prm.wcf_lo = wcf_lo;
    prm.w1f_hi = w1f_hi; prm.w1f_lo = w1f_lo;
    prm.b_l = b_l; prm.b_c = b_c; prm.b1 = b1; prm.W2 = W2; prm.b2 = b2;
    prm.c = c; prm.h_f32 = h_f32; prm.buf = buf; prm.part_p = part_p; prm.y = y;
    prm.hfa_hi = hfa_hi; prm.hfa_lo = hfa_lo;
    prm.hfb_hi = hfb_hi; prm.hfb_lo = hfb_lo;
    prm.ctx_hi = ctx_hi; prm.ctx_lo = ctx_lo;
    prm.sync = sync;

    k_persist<<<dim3(NBLK), dim3(256), 0, stream>>>(prm);
}

// Round 7
// 4609.462 us; speedup vs baseline: 2.1046x; 2.1046x over previous
//
#include <hip/hip_runtime.h>
#include <hip/hip_bf16.h>
#include <math.h>

// Problem sizes
#define Bz   512
#define Tz   128
#define INz  64
#define Hz   512
#define TSz  32
#define PLz  32
#define BH   (Bz * Hz)          // 262144
#define NBLK 256
#define PF   4

typedef unsigned short u16;
typedef unsigned long long u64;
typedef __attribute__((ext_vector_type(8)))  short short8;
typedef __attribute__((ext_vector_type(16))) float floatx16;

static __device__ __forceinline__ void split_bf(float w, u16& hi, u16& lo) {
    __hip_bfloat16 h = __float2bfloat16(w);
    hi = *reinterpret_cast<u16*>(&h);
    float r = w - __bfloat162float(h);
    __hip_bfloat16 l = __float2bfloat16(r);
    lo = *reinterpret_cast<u16*>(&l);
}

// ---- coherent (sc1, MALL) access helpers: relaxed agent-scope atomics ----
union U64x2 { u64 q[2]; short8 v; };
union F2U { u64 q; float f[2]; };
union FU  { unsigned u; float f; };

static __device__ __forceinline__ short8 ald16(const u16* p) {
    U64x2 u;
    u.q[0] = __hip_atomic_load((const u64*)p,     __ATOMIC_RELAXED, __HIP_MEMORY_SCOPE_AGENT);
    u.q[1] = __hip_atomic_load((const u64*)p + 1, __ATOMIC_RELAXED, __HIP_MEMORY_SCOPE_AGENT);
    return u.v;
}
static __device__ __forceinline__ void ast64(u16* p, u64 v) {
    __hip_atomic_store((u64*)p, v, __ATOMIC_RELAXED, __HIP_MEMORY_SCOPE_AGENT);
}
static __device__ __forceinline__ void ast64f(float* p, float a, float b) {
    F2U u; u.f[0] = a; u.f[1] = b;
    __hip_atomic_store((u64*)p, u.q, __ATOMIC_RELAXED, __HIP_MEMORY_SCOPE_AGENT);
}
static __device__ __forceinline__ float aldf(const float* p) {
    FU c; c.u = __hip_atomic_load((const unsigned*)p, __ATOMIC_RELAXED, __HIP_MEMORY_SCOPE_AGENT);
    return c.f;
}
static __device__ __forceinline__ void astf(float* p, float v) {
    FU c; c.f = v;
    __hip_atomic_store((unsigned*)p, c.u, __ATOMIC_RELAXED, __HIP_MEMORY_SCOPE_AGENT);
}

// ---------------- init ----------------
__global__ __launch_bounds__(256) void k_init(float* __restrict__ c,
                                              u16* __restrict__ hf_hi,
                                              u16* __restrict__ hf_lo,
                                              unsigned* __restrict__ sync) {
    const int i = blockIdx.x * 256 + threadIdx.x;
    if (i < BH) { c[i] = 0.f; hf_hi[i] = 0; hf_lo[i] = 0; }
    if (i < 2048) sync[i] = 0;
}

// ---------------- prep kernels (unchanged) ----------------
__global__ __launch_bounds__(256) void k_prep_wenc(const float* __restrict__ W_ih,
                                                   const float* __restrict__ W_hh,
                                                   u16* __restrict__ wf_hi,
                                                   u16* __restrict__ wf_lo) {
    const int idx = blockIdx.x * 256 + threadIdx.x;
    const int lane = idx & 63;
    const int g = (idx >> 6) % 36;
    const int cb = idx / (36 * 64);
    const int C = cb * 32 + (lane & 31);
    const int gate = ((C >> 4) & 3) * 512 + (C >> 6) * 16 + (C & 15);
    const int kh = lane >> 5;
    const size_t base = (size_t)idx * 8;
    #pragma unroll
    for (int e = 0; e < 8; ++e) {
        const int k = g * 16 + kh * 8 + e;
        const float w = (k < 64) ? W_ih[(size_t)gate * 64 + k]
                                 : W_hh[(size_t)gate * 512 + (k - 64)];
        u16 hi, lo; split_bf(w, hi, lo);
        wf_hi[base + e] = hi; wf_lo[base + e] = lo;
    }
}

__global__ __launch_bounds__(256) void k_prep_wc(const float* __restrict__ Wc_ih,
                                                 const float* __restrict__ Wc_hh,
                                                 u16* __restrict__ wf_hi,
                                                 u16* __restrict__ wf_lo) {
    const int idx = blockIdx.x * 256 + threadIdx.x;
    const int lane = idx & 63;
    const int cb = idx / (32 * 64);
    const int g = (idx >> 6) % 32;
    const int C = cb * 32 + (lane & 31);
    const int gate = ((C >> 4) & 3) * 512 + (C >> 6) * 16 + (C & 15);
    const int kh = lane >> 5;
    const size_t base = (size_t)idx * 8;
    #pragma unroll
    for (int e = 0; e < 8; ++e) {
        const int k = g * 16 + kh * 8 + e;
        const float w = Wc_ih[(size_t)gate * 512 + k] + Wc_hh[(size_t)gate * 512 + k];
        u16 hi, lo; split_bf(w, hi, lo);
        wf_hi[base + e] = hi; wf_lo[base + e] = lo;
    }
}

__global__ __launch_bounds__(256) void k_prep_w1(const float* __restrict__ W1,
                                                 u16* __restrict__ wf_hi,
                                                 u16* __restrict__ wf_lo) {
    const int idx = blockIdx.x * 256 + threadIdx.x;
    const int lane = idx & 63;
    const int cb = idx / (64 * 64);
    const int g = (idx >> 6) % 64;
    const int n = cb * 32 + (lane & 31);
    const int kh = lane >> 5;
    const size_t base = (size_t)idx * 8;
    #pragma unroll
    for (int e = 0; e < 8; ++e) {
        const int k = g * 16 + kh * 8 + e;
        const float w = W1[(size_t)n * 1024 + k];
        u16 hi, lo; split_bf(w, hi, lo);
        wf_hi[base + e] = hi; wf_lo[base + e] = lo;
    }
}

__global__ __launch_bounds__(256) void k_prep_x(const float* __restrict__ x,
                                                u16* __restrict__ xf_hi,
                                                u16* __restrict__ xf_lo) {
    const int idx = blockIdx.x * 256 + threadIdx.x;
    const int lane = idx & 63;
    const int g = (idx >> 6) & 3;
    const int rb = (idx >> 8) & 15;
    const int t = idx >> 12;
    const int b = rb * 32 + (lane & 31);
    const int kh = lane >> 5;
    const size_t base = (size_t)idx * 8;
    #pragma unroll
    for (int e = 0; e < 8; ++e) {
        const int i = g * 16 + kh * 8 + e;
        const float w = x[((size_t)b * Tz + t) * INz + i];
        u16 hi, lo; split_bf(w, hi, lo);
        xf_hi[base + e] = hi; xf_lo[base + e] = lo;
    }
}

// ---------------- fence-free two-level grid barrier (monotonic counters) ----------------
// sync[0]=generation; sync[32+g*32]=group counter g (g=0..15); sync[32+16*32]=root.
// NO release/acquire fences -> NO buffer_wbl2 / buffer_inv -> L2 stays hot.
// Safe because: all cross-block data uses sc1 atomics (coherence point), and
// __syncthreads drains each wave's vmem before the arrival atomic issues.
static __device__ __forceinline__ void gsync(unsigned* sync, unsigned nb, int bid) {
    __syncthreads();
    if (threadIdx.x == 0) {
        unsigned* gcnt = sync + 32 + (bid >> 4) * 32;
        unsigned* rcnt = sync + 32 + 16 * 32;
        const unsigned a = __hip_atomic_fetch_add(gcnt, 1u, __ATOMIC_RELAXED, __HIP_MEMORY_SCOPE_AGENT);
        if (a == nb * 16u + 15u) {
            const unsigned r = __hip_atomic_fetch_add(rcnt, 1u, __ATOMIC_RELAXED, __HIP_MEMORY_SCOPE_AGENT);
            if (r == nb * 16u + 15u)
                __hip_atomic_store(sync, nb + 1u, __ATOMIC_RELAXED, __HIP_MEMORY_SCOPE_AGENT);
        }
        while (__hip_atomic_load(sync, __ATOMIC_RELAXED, __HIP_MEMORY_SCOPE_AGENT) <= nb)
            __builtin_amdgcn_s_sleep(2);
    }
    __syncthreads();
}

// ---------------- gates + cell phase ----------------
// Weights/x/bias: normal cached loads (read-only, L2-resident).
// h fragments in/out, buf, h_f32: sc1 atomics (cross-block).
// c: normal (block-private: same (b,j)->block mapping every step).
template<int NG, int GX>
__device__ __forceinline__ void gates_phase(
    const u16* __restrict__ xf_hi, const u16* __restrict__ xf_lo, int t,
    const u16* __restrict__ wf_hi, const u16* __restrict__ wf_lo,
    const u16* __restrict__ hin_hi, const u16* __restrict__ hin_lo,
    const float* __restrict__ bias,
    float* __restrict__ c, float* __restrict__ h_f32,
    u16* __restrict__ hout_hi, u16* __restrict__ hout_lo,
    float* __restrict__ buf, int slot,
    float* Gt, int bid, int tid)
{
    const int lane = tid & 63, wid = tid >> 6;
    const int wr = wid >> 1, wc = wid & 1;
    const int ji = bid & 31, bi = bid >> 5;
    const int rbIdx = bi * 2 + wr;
    const int cbIdx = ji * 2 + wc;

    floatx16 acc0, acc1, acc2;
    #pragma unroll
    for (int i = 0; i < 16; ++i) { acc0[i] = 0.f; acc1[i] = 0.f; acc2[i] = 0.f; }

    const u16* pb_hi = wf_hi + ((size_t)cbIdx * NG) * 512 + lane * 8;
    const u16* pb_lo = wf_lo + ((size_t)cbIdx * NG) * 512 + lane * 8;

    short8 ah[PF], al[PF], bh[PF], bl[PF];

    #pragma unroll
    for (int g = 0; g < NG + PF; ++g) {
        if (g >= PF) {   // consume granule g-PF
            const int s = (g - PF) & (PF - 1);
            acc0 = __builtin_amdgcn_mfma_f32_32x32x16_bf16(ah[s], bh[s], acc0, 0, 0, 0);
            acc1 = __builtin_amdgcn_mfma_f32_32x32x16_bf16(ah[s], bl[s], acc1, 0, 0, 0);
            acc2 = __builtin_amdgcn_mfma_f32_32x32x16_bf16(al[s], bh[s], acc2, 0, 0, 0);
        }
        if (g < NG) {    // refill with granule g
            const int s = g & (PF - 1);
            if (g < GX) {   // x part: read-only, normal cached loads
                const size_t off = ((((size_t)t * 16 + rbIdx) * 4 + g) * 64 + lane) * 8;
                ah[s] = *(const short8*)(xf_hi + off);
                al[s] = *(const short8*)(xf_lo + off);
            } else {        // h part: cross-block, sc1
                const size_t off = (((size_t)rbIdx * 32 + (g - GX)) * 64 + lane) * 8;
                ah[s] = ald16(hin_hi + off);
                al[s] = ald16(hin_lo + off);
            }
            bh[s] = *(const short8*)(pb_hi + (size_t)g * 512);
            bl[s] = *(const short8*)(pb_lo + (size_t)g * 512);
        }
    }
    #pragma unroll
    for (int i = 0; i < 16; ++i) acc0[i] += acc1[i] + acc2[i];

    {   // dump 32x32 frags to Gt[64][65] (stride 65: conflict-free cell reads)
        const int col = wc * 32 + (lane & 31);
        const int rbase = wr * 32 + 4 * (lane >> 5);
        #pragma unroll
        for (int r = 0; r < 16; ++r)
            Gt[(rbase + (r & 3) + 8 * (r >> 2)) * 65 + col] = acc0[r];
    }
    __syncthreads();

    // cell update: thread -> (b = bi*64 + tid>>2, 4 consecutive j)
    {
        const int bl2 = tid >> 2, jq = tid & 3;
        const int b = bi * 64 + bl2;
        const int j0 = ji * 16 + jq * 4;
        const size_t co = (size_t)b * Hz + j0;
        float4 cv = *(const float4*)&c[co];
        float ce[4] = {cv.x, cv.y, cv.z, cv.w};
        float hn4[4];
        u64 phi = 0, plo = 0;
        #pragma unroll
        for (int e = 0; e < 4; ++e) {
            const int jj = jq * 4 + e;
            const float gi = Gt[bl2 * 65 + jj]      + bias[j0 + e];
            const float gf = Gt[bl2 * 65 + 16 + jj] + bias[512 + j0 + e];
            const float gg = Gt[bl2 * 65 + 32 + jj] + bias[1024 + j0 + e];
            const float go = Gt[bl2 * 65 + 48 + jj] + bias[1536 + j0 + e];
            const float si = 1.f / (1.f + __expf(-gi));
            const float sf = 1.f / (1.f + __expf(-gf));
            const float so = 1.f / (1.f + __expf(-go));
            const float cn = sf * ce[e] + si * tanhf(gg);
            const float hn = so * tanhf(cn);
            ce[e] = cn; hn4[e] = hn;
            u16 hi, lo; split_bf(hn, hi, lo);
            phi |= (u64)hi << (16 * e);
            plo |= (u64)lo << (16 * e);
        }
        float4 cw; cw.x = ce[0]; cw.y = ce[1]; cw.z = ce[2]; cw.w = ce[3];
        *(float4*)&c[co] = cw;
        // fragment-major h (sc1, 8B packed)
        const int rb = b >> 5, gran = j0 >> 4;
        const int fl = ((j0 >> 3) & 1) * 32 + (b & 31);
        const size_t fo = (((size_t)rb * 32 + gran) * 64 + fl) * 8 + (j0 & 7);
        ast64(hout_hi + fo, phi);
        ast64(hout_lo + fo, plo);
        if (slot >= 0) {
            float* bp = buf + ((size_t)b * TSz + slot) * Hz + j0;
            ast64f(bp, hn4[0], hn4[1]);
            ast64f(bp + 2, hn4[2], hn4[3]);
        } else {
            float* hp = h_f32 + co;
            ast64f(hp, hn4[0], hn4[1]);
            ast64f(hp + 2, hn4[2], hn4[3]);
        }
    }
}

// ---------------- attention phase: 2 batches per block ----------------
__device__ __forceinline__ void attn_phase(const float* __restrict__ h_f32,
                                           float* __restrict__ buf,
                                           u16* __restrict__ ctx_hi, u16* __restrict__ ctx_lo,
                                           int base, float* lds, int bid, int tid) {
    float* sh = lds + (tid >> 7) * 544;
    float* sa = sh + 512;
    const int b = bid * 2 + (tid >> 7);
    const int t7 = tid & 127;
    for (int i = t7; i < 512; i += 128) sh[i] = aldf(&h_f32[(size_t)b * Hz + i]);
    __syncthreads();
    {   // 32 scores, 4 lanes each (sc1 buf reads)
        const int s = t7 >> 2, l4 = t7 & 3;
        const float* br = buf + ((size_t)b * TSz + ((base + s) & 31)) * Hz;
        float p = 0.f;
        #pragma unroll 16
        for (int j = l4; j < 512; j += 4) p = fmaf(sh[j], aldf(&br[j]), p);
        p += __shfl_xor(p, 1); p += __shfl_xor(p, 2);
        if (l4 == 0) sa[s] = p;
    }
    __syncthreads();
    if (t7 < 32) {   // softmax over 32
        const float v = sa[t7];
        float m = v;
        #pragma unroll
        for (int d = 1; d < 32; d <<= 1) m = fmaxf(m, __shfl_xor(m, d));
        const float e = __expf(v - m);
        float ss = e;
        #pragma unroll
        for (int d = 1; d < 32; d <<= 1) ss += __shfl_xor(ss, d);
        sa[t7] = e / ss;
    }
    __syncthreads();
    {   // ctx: thread t7 owns j = t7*4 .. +3 -> packed sc1 fragment store
        const int j0 = t7 * 4;
        float a4[4] = {0.f, 0.f, 0.f, 0.f};
        #pragma unroll
        for (int s2 = 0; s2 < TSz; ++s2) {
            const float w = sa[s2];
            const float* bp = buf + ((size_t)b * TSz + ((base + s2) & 31)) * Hz + j0;
            a4[0] = fmaf(w, aldf(bp), a4[0]);
            a4[1] = fmaf(w, aldf(bp + 1), a4[1]);
            a4[2] = fmaf(w, aldf(bp + 2), a4[2]);
            a4[3] = fmaf(w, aldf(bp + 3), a4[3]);
        }
        u64 phi = 0, plo = 0;
        #pragma unroll
        for (int e = 0; e < 4; ++e) {
            u16 hi, lo; split_bf(a4[e], hi, lo);
            phi |= (u64)hi << (16 * e);
            plo |= (u64)lo << (16 * e);
        }
        const int rb = b >> 5, gran = j0 >> 4;
        const int fl = ((j0 >> 3) & 1) * 32 + (b & 31);
        const size_t fo = (((size_t)rb * 32 + gran) * 64 + fl) * 8 + (j0 & 7);
        ast64(ctx_hi + fo, phi);
        ast64(ctx_lo + fo, plo);
    }
    __syncthreads();
    #pragma unroll
    for (int pass = 0; pass < 2; ++pass) {   // append h_t to slot `base` (sc1)
        const int i = pass * 256 + t7 * 2;
        ast64f(buf + ((size_t)b * TSz + base) * Hz + i, sh[i], sh[i + 1]);
    }
}

// ---------------- MLP + partial out phase ----------------
__device__ __forceinline__ void mlp_phase(
    const u16* __restrict__ ctx_hi, const u16* __restrict__ ctx_lo,
    const u16* __restrict__ h_hi,   const u16* __restrict__ h_lo,
    const u16* __restrict__ w1_hi,  const u16* __restrict__ w1_lo,
    const float* __restrict__ b1, const float* __restrict__ W2,
    float* __restrict__ part_p, float* lds, int bid, int tid)
{
    const int lane = tid & 63, w = tid >> 6;
    const int ni = bid & 15, bi2 = bid >> 4;

    floatx16 acc0, acc1, acc2;
    #pragma unroll
    for (int i = 0; i < 16; ++i) { acc0[i] = 0.f; acc1[i] = 0.f; acc2[i] = 0.f; }

    short8 ah[PF], al[PF], bh[PF], bl[PF];

    #pragma unroll
    for (int gg = 0; gg < 16 + PF; ++gg) {
        if (gg >= PF) {
            const int s = (gg - PF) & (PF - 1);
            acc0 = __builtin_amdgcn_mfma_f32_32x32x16_bf16(ah[s], bh[s], acc0, 0, 0, 0);
            acc1 = __builtin_amdgcn_mfma_f32_32x32x16_bf16(ah[s], bl[s], acc1, 0, 0, 0);
            acc2 = __builtin_amdgcn_mfma_f32_32x32x16_bf16(al[s], bh[s], acc2, 0, 0, 0);
        }
        if (gg < 16) {
            const int s = gg & (PF - 1);
            const int g = w * 16 + gg;   // wave-split K
            if (g < 32) {
                const size_t off = (((size_t)bi2 * 32 + g) * 64 + lane) * 8;
                ah[s] = ald16(ctx_hi + off);
                al[s] = ald16(ctx_lo + off);
            } else {
                const size_t off = (((size_t)bi2 * 32 + (g - 32)) * 64 + lane) * 8;
                ah[s] = ald16(h_hi + off);
                al[s] = ald16(h_lo + off);
            }
            const size_t boff = (((size_t)ni * 64 + g) * 64 + lane) * 8;
            bh[s] = *(const short8*)(w1_hi + boff);   // W1: read-only, cached
            bl[s] = *(const short8*)(w1_lo + boff);
        }
    }
    #pragma unroll
    for (int i = 0; i < 16; ++i) acc0[i] += acc1[i] + acc2[i];

    {   // per-wave 32x32 partial -> lds[w][row][col]
        const int col = lane & 31;
        const int rb4 = 4 * (lane >> 5);
        #pragma unroll
        for (int r = 0; r < 16; ++r)
            lds[w * 1024 + (rb4 + (r & 3) + 8 * (r >> 2)) * 32 + col] = acc0[r];
    }
    __syncthreads();

    // reduce 4 wave-partials + bias, tanh, dot with W2 slice -> part_p[ni][b] (sc1)
    const int row = tid >> 3, l8 = tid & 7;
    float a = 0.f;
    #pragma unroll
    for (int jj = 0; jj < 4; ++jj) {
        const int col = l8 * 4 + jj;
        const int ncol = ni * 32 + col;
        const float pre = lds[row * 32 + col] + lds[1024 + row * 32 + col]
                        + lds[2048 + row * 32 + col] + lds[3072 + row * 32 + col] + b1[ncol];
        a = fmaf(tanhf(pre), W2[ncol], a);
    }
    a += __shfl_xor(a, 1); a += __shfl_xor(a, 2); a += __shfl_xor(a, 4);
    if (l8 == 0) astf(&part_p[ni * 512 + bi2 * 32 + row], a);
}

__device__ __forceinline__ void y_reduce(const float* __restrict__ part_p,
                                         const float* __restrict__ b2,
                                         float* __restrict__ y, int s, int bid, int tid) {
    if (tid < 2) {
        const int b = bid * 2 + tid;
        float a = b2[0];
        #pragma unroll
        for (int ni = 0; ni < 16; ++ni) a += aldf(&part_p[ni * 512 + b]);
        y[(size_t)b * PLz + s] = a;   // normal store; kernel-end flush covers host read
    }
}

// ---------------- the persistent kernel ----------------
struct KParams {
    const u16 *xf_hi, *xf_lo, *wf_hi, *wf_lo, *wcf_hi, *wcf_lo, *w1f_hi, *w1f_lo;
    const float *b_l, *b_c, *b1, *W2, *b2;
    float *c, *h_f32, *buf, *part_p, *y;
    u16 *hfa_hi, *hfa_lo, *hfb_hi, *hfb_lo, *ctx_hi, *ctx_lo;
    unsigned *sync;
};

__global__ __launch_bounds__(256) void k_persist(KParams p) {
    __shared__ float lds[4160];
    const int bid = blockIdx.x;
    const int tid = threadIdx.x;
    unsigned nb = 0;

    // encoder: 128 steps
    for (int t = 0; t < Tz; ++t) {
        const u16* in_hi = (t & 1) ? p.hfb_hi : p.hfa_hi;
        const u16* in_lo = (t & 1) ? p.hfb_lo : p.hfa_lo;
        u16* out_hi = (t & 1) ? p.hfa_hi : p.hfb_hi;
        u16* out_lo = (t & 1) ? p.hfa_lo : p.hfb_lo;
        gates_phase<36, 4>(p.xf_hi, p.xf_lo, t, p.wf_hi, p.wf_lo, in_hi, in_lo,
                           p.b_l, p.c, nullptr, out_hi, out_lo, p.buf, t & 31,
                           lds, bid, tid);
        gsync(p.sync, nb++, bid);
    }
    // decoder: 32 iterations (gates | attn | mlp+out)
    for (int s = 0; s < PLz; ++s) {
        if (s > 0) y_reduce(p.part_p, p.b2, p.y, s - 1, bid, tid);
        const u16* in_hi = (s & 1) ? p.hfb_hi : p.hfa_hi;
        const u16* in_lo = (s & 1) ? p.hfb_lo : p.hfa_lo;
        u16* out_hi = (s & 1) ? p.hfa_hi : p.hfb_hi;
        u16* out_lo = (s & 1) ? p.hfa_lo : p.hfb_lo;
        gates_phase<32, 0>(nullptr, nullptr, 0, p.wcf_hi, p.wcf_lo, in_hi, in_lo,
                           p.b_c, p.c, p.h_f32, out_hi, out_lo, nullptr, -1,
                           lds, bid, tid);
        gsync(p.sync, nb++, bid);
        attn_phase(p.h_f32, p.buf, p.ctx_hi, p.ctx_lo, s & 31, lds, bid, tid);
        gsync(p.sync, nb++, bid);
        mlp_phase(p.ctx_hi, p.ctx_lo, out_hi, out_lo, p.w1f_hi, p.w1f_lo,
                  p.b1, p.W2, p.part_p, lds, bid, tid);
        gsync(p.sync, nb++, bid);
    }
    y_reduce(p.part_p, p.b2, p.y, PLz - 1, bid, tid);
}

extern "C" void kernel_launch(void* const* d_in, const int* in_sizes, int n_in,
                              void* d_out, int out_size, void* d_ws, size_t ws_size,
                              hipStream_t stream) {
    (void)in_sizes; (void)n_in; (void)out_size; (void)ws_size;
    const float* x     = (const float*)d_in[0];
    const float* W_ih  = (const float*)d_in[1];
    const float* W_hh  = (const float*)d_in[2];
    const float* b_l   = (const float*)d_in[3];
    const float* Wc_ih = (const float*)d_in[4];
    const float* Wc_hh = (const float*)d_in[5];
    const float* b_c   = (const float*)d_in[6];
    const float* W1    = (const float*)d_in[7];
    const float* b1    = (const float*)d_in[8];
    const float* W2    = (const float*)d_in[9];
    const float* b2    = (const float*)d_in[10];
    float* y = (float*)d_out;

    float* w = (float*)d_ws;
    float* c      = w;                          // BH
    float* h_f32  = w + BH;                     // BH
    float* buf    = w + 2 * (size_t)BH;         // 32*BH
    float* part_p = w + 34 * (size_t)BH;        // 8192
    unsigned* sync = (unsigned*)(w + 34 * (size_t)BH + 8192);   // 2048 u32
    u16* us = (u16*)(w + 34 * (size_t)BH + 8192 + 2048);
    u16* hfa_hi = us;  us += BH;
    u16* hfa_lo = us;  us += BH;
    u16* hfb_hi = us;  us += BH;
    u16* hfb_lo = us;  us += BH;
    u16* ctx_hi = us;  us += BH;
    u16* ctx_lo = us;  us += BH;
    u16* xf_hi = us;   us += 4194304;
    u16* xf_lo = us;   us += 4194304;
    u16* wf_hi = us;   us += 1179648;
    u16* wf_lo = us;   us += 1179648;
    u16* wcf_hi = us;  us += 1048576;
    u16* wcf_lo = us;  us += 1048576;
    u16* w1f_hi = us;  us += 524288;
    u16* w1f_lo = us;  us += 524288;

    k_init     <<<1024, 256, 0, stream>>>(c, hfa_hi, hfa_lo, sync);
    k_prep_wenc<<<576,  256, 0, stream>>>(W_ih, W_hh, wf_hi, wf_lo);
    k_prep_wc  <<<512,  256, 0, stream>>>(Wc_ih, Wc_hh, wcf_hi, wcf_lo);
    k_prep_w1  <<<256,  256, 0, stream>>>(W1, w1f_hi, w1f_lo);
    k_prep_x   <<<2048, 256, 0, stream>>>(x, xf_hi, xf_lo);

    KParams prm;
    prm.xf_hi = xf_hi;   prm.xf_lo = xf_lo;
    prm.wf_hi = wf_hi;   prm.wf_lo = wf_lo;
    prm.wcf_hi = wcf_hi; prm.wcf_lo = wcf_lo;
    prm.w1f_hi = w1f_hi; prm.w1f_lo = w1f_lo;
    prm.b_l = b_l; prm.b_c = b_c; prm.b1 = b1; prm.W2 = W2; prm.b2 = b2;
    prm.c = c; prm.h_f32 = h_f32; prm.buf = buf; prm.part_p = part_p; prm.y = y;
    prm.hfa_hi = hfa_hi; prm.hfa_lo = hfa_lo;
    prm.hfb_hi = hfb_hi; prm.hfb_lo = hfb_lo;
    prm.ctx_hi = ctx_hi; prm.ctx_lo = ctx_lo;
    prm.sync = sync;

    k_persist<<<dim3(NBLK), dim3(256), 0, stream>>>(prm);
}

// Round 8
// 4198.400 us; speedup vs baseline: 2.3106x; 1.0979x over previous
//
#include <hip/hip_runtime.h>
#include <hip/hip_bf16.h>
#include <math.h>

// Problem sizes
#define Bz   512
#define Tz   128
#define INz  64
#define Hz   512
#define TSz  32
#define PLz  32
#define BH   (Bz * Hz)          // 262144
#define NBLK 256
#define PF   4

typedef unsigned short u16;
typedef unsigned long long u64;
typedef __attribute__((ext_vector_type(8)))  short short8;
typedef __attribute__((ext_vector_type(16))) float floatx16;

static __device__ __forceinline__ void split_bf(float w, u16& hi, u16& lo) {
    __hip_bfloat16 h = __float2bfloat16(w);
    hi = *reinterpret_cast<u16*>(&h);
    float r = w - __bfloat162float(h);
    __hip_bfloat16 l = __float2bfloat16(r);
    lo = *reinterpret_cast<u16*>(&l);
}

// ---- sc1 (coherence-point) STORE helpers: relaxed agent-scope atomics.
// Writes bypass/write through L2 -> L2 never holds dirty shared lines ->
// acquire fence (buffer_inv, no wbl2) at barriers is safe and cheap.
union F2U { u64 q; float f[2]; };
union FU  { unsigned u; float f; };

static __device__ __forceinline__ void ast64(u16* p, u64 v) {
    __hip_atomic_store((u64*)p, v, __ATOMIC_RELAXED, __HIP_MEMORY_SCOPE_AGENT);
}
static __device__ __forceinline__ void ast64f(float* p, float a, float b) {
    F2U u; u.f[0] = a; u.f[1] = b;
    __hip_atomic_store((u64*)p, u.q, __ATOMIC_RELAXED, __HIP_MEMORY_SCOPE_AGENT);
}
static __device__ __forceinline__ void astf(float* p, float v) {
    FU c; c.f = v;
    __hip_atomic_store((unsigned*)p, c.u, __ATOMIC_RELAXED, __HIP_MEMORY_SCOPE_AGENT);
}
static __device__ __forceinline__ unsigned aldu(const unsigned* p) {
    return __hip_atomic_load(p, __ATOMIC_RELAXED, __HIP_MEMORY_SCOPE_AGENT);
}
static __device__ __forceinline__ void astu(unsigned* p, unsigned v) {
    __hip_atomic_store(p, v, __ATOMIC_RELAXED, __HIP_MEMORY_SCOPE_AGENT);
}

// ---------------- init: zero h fragments + sync area ----------------
__global__ __launch_bounds__(256) void k_init(u16* __restrict__ hf_hi,
                                              u16* __restrict__ hf_lo,
                                              unsigned* __restrict__ sync) {
    const int i = blockIdx.x * 256 + threadIdx.x;
    if (i < BH) { hf_hi[i] = 0; hf_lo[i] = 0; }
    if (i < 8192) sync[i] = 0;
}

// ---------------- prep kernels (unchanged) ----------------
__global__ __launch_bounds__(256) void k_prep_wenc(const float* __restrict__ W_ih,
                                                   const float* __restrict__ W_hh,
                                                   u16* __restrict__ wf_hi,
                                                   u16* __restrict__ wf_lo) {
    const int idx = blockIdx.x * 256 + threadIdx.x;
    const int lane = idx & 63;
    const int g = (idx >> 6) % 36;
    const int cb = idx / (36 * 64);
    const int C = cb * 32 + (lane & 31);
    const int gate = ((C >> 4) & 3) * 512 + (C >> 6) * 16 + (C & 15);
    const int kh = lane >> 5;
    const size_t base = (size_t)idx * 8;
    #pragma unroll
    for (int e = 0; e < 8; ++e) {
        const int k = g * 16 + kh * 8 + e;
        const float w = (k < 64) ? W_ih[(size_t)gate * 64 + k]
                                 : W_hh[(size_t)gate * 512 + (k - 64)];
        u16 hi, lo; split_bf(w, hi, lo);
        wf_hi[base + e] = hi; wf_lo[base + e] = lo;
    }
}

__global__ __launch_bounds__(256) void k_prep_wc(const float* __restrict__ Wc_ih,
                                                 const float* __restrict__ Wc_hh,
                                                 u16* __restrict__ wf_hi,
                                                 u16* __restrict__ wf_lo) {
    const int idx = blockIdx.x * 256 + threadIdx.x;
    const int lane = idx & 63;
    const int cb = idx / (32 * 64);
    const int g = (idx >> 6) % 32;
    const int C = cb * 32 + (lane & 31);
    const int gate = ((C >> 4) & 3) * 512 + (C >> 6) * 16 + (C & 15);
    const int kh = lane >> 5;
    const size_t base = (size_t)idx * 8;
    #pragma unroll
    for (int e = 0; e < 8; ++e) {
        const int k = g * 16 + kh * 8 + e;
        const float w = Wc_ih[(size_t)gate * 512 + k] + Wc_hh[(size_t)gate * 512 + k];
        u16 hi, lo; split_bf(w, hi, lo);
        wf_hi[base + e] = hi; wf_lo[base + e] = lo;
    }
}

__global__ __launch_bounds__(256) void k_prep_w1(const float* __restrict__ W1,
                                                 u16* __restrict__ wf_hi,
                                                 u16* __restrict__ wf_lo) {
    const int idx = blockIdx.x * 256 + threadIdx.x;
    const int lane = idx & 63;
    const int cb = idx / (64 * 64);
    const int g = (idx >> 6) % 64;
    const int n = cb * 32 + (lane & 31);
    const int kh = lane >> 5;
    const size_t base = (size_t)idx * 8;
    #pragma unroll
    for (int e = 0; e < 8; ++e) {
        const int k = g * 16 + kh * 8 + e;
        const float w = W1[(size_t)n * 1024 + k];
        u16 hi, lo; split_bf(w, hi, lo);
        wf_hi[base + e] = hi; wf_lo[base + e] = lo;
    }
}

__global__ __launch_bounds__(256) void k_prep_x(const float* __restrict__ x,
                                                u16* __restrict__ xf_hi,
                                                u16* __restrict__ xf_lo) {
    const int idx = blockIdx.x * 256 + threadIdx.x;
    const int lane = idx & 63;
    const int g = (idx >> 6) & 3;
    const int rb = (idx >> 8) & 15;
    const int t = idx >> 12;
    const int b = rb * 32 + (lane & 31);
    const int kh = lane >> 5;
    const size_t base = (size_t)idx * 8;
    #pragma unroll
    for (int e = 0; e < 8; ++e) {
        const int i = g * 16 + kh * 8 + e;
        const float w = x[((size_t)b * Tz + t) * INz + i];
        u16 hi, lo; split_bf(w, hi, lo);
        xf_hi[base + e] = hi; xf_lo[base + e] = lo;
    }
}

// ---------------- grid barrier: slot-arrival, root scan, group release ----------------
// sync layout (u32): arr = sync+64, 256 slots stride 16 (64B apart);
//                    grel = sync+64+4096, 16 words stride 16.
// No RMW (no wbl2), no release fence; __syncthreads drains vmem (sc1 stores done).
// Exit: acquire fence -> buffer_inv (drop stale clean lines; nothing dirty exists).
static __device__ __forceinline__ void gsync(unsigned* sync, unsigned target, int bid) {
    __syncthreads();
    const int tid = threadIdx.x;
    unsigned* arr  = sync + 64;
    unsigned* grel = sync + 64 + 4096;
    if (bid == 0) {
        if (tid < 64) {
            if (tid == 0) astu(&arr[0], target);
            bool done = false;
            while (!done) {
                unsigned mn = 0xffffffffu;
                #pragma unroll
                for (int k = 0; k < 4; ++k) {
                    const unsigned v = aldu(&arr[(tid * 4 + k) * 16]);
                    mn = v < mn ? v : mn;
                }
                done = (bool)__all((int)(mn >= target));
                if (!done) __builtin_amdgcn_s_sleep(1);
            }
            if (tid < 16) astu(&grel[tid * 16], target);
        }
    } else {
        if (tid == 0) {
            astu(&arr[bid * 16], target);
            while (aldu(&grel[(bid >> 4) * 16]) < target)
                __builtin_amdgcn_s_sleep(2);
        }
    }
    if (tid == 0) __builtin_amdgcn_fence(__ATOMIC_ACQUIRE, "agent");   // buffer_inv only
    __syncthreads();
}

// ---------------- gates + cell phase ----------------
// ALL reads normal cached (weights/x/h); cross-block stores sc1; c in registers.
template<int NG, int GX>
__device__ __forceinline__ void gates_phase(
    const u16* __restrict__ xf_hi, const u16* __restrict__ xf_lo, int t,
    const u16* __restrict__ wf_hi, const u16* __restrict__ wf_lo,
    const u16* __restrict__ hin_hi, const u16* __restrict__ hin_lo,
    const float* __restrict__ bias,
    float (&c4)[4], float* __restrict__ h_f32,
    u16* __restrict__ hout_hi, u16* __restrict__ hout_lo,
    float* __restrict__ buf, int slot,
    float* Gt, int bid, int tid)
{
    const int lane = tid & 63, wid = tid >> 6;
    const int wr = wid >> 1, wc = wid & 1;
    const int ji = bid & 31, bi = bid >> 5;
    const int rbIdx = bi * 2 + wr;
    const int cbIdx = ji * 2 + wc;

    floatx16 acc0, acc1, acc2;
    #pragma unroll
    for (int i = 0; i < 16; ++i) { acc0[i] = 0.f; acc1[i] = 0.f; acc2[i] = 0.f; }

    const u16* pb_hi = wf_hi + ((size_t)cbIdx * NG) * 512 + lane * 8;
    const u16* pb_lo = wf_lo + ((size_t)cbIdx * NG) * 512 + lane * 8;

    short8 ah[PF], al[PF], bh[PF], bl[PF];

    #pragma unroll
    for (int g = 0; g < NG + PF; ++g) {
        if (g >= PF) {   // consume granule g-PF
            const int s = (g - PF) & (PF - 1);
            acc0 = __builtin_amdgcn_mfma_f32_32x32x16_bf16(ah[s], bh[s], acc0, 0, 0, 0);
            acc1 = __builtin_amdgcn_mfma_f32_32x32x16_bf16(ah[s], bl[s], acc1, 0, 0, 0);
            acc2 = __builtin_amdgcn_mfma_f32_32x32x16_bf16(al[s], bh[s], acc2, 0, 0, 0);
        }
        if (g < NG) {    // refill with granule g (all normal cached loads)
            const int s = g & (PF - 1);
            const u16* pa_hi;
            const u16* pa_lo;
            if (g < GX) {
                const size_t off = ((((size_t)t * 16 + rbIdx) * 4 + g) * 64 + lane) * 8;
                pa_hi = xf_hi + off; pa_lo = xf_lo + off;
            } else {
                const size_t off = (((size_t)rbIdx * 32 + (g - GX)) * 64 + lane) * 8;
                pa_hi = hin_hi + off; pa_lo = hin_lo + off;
            }
            ah[s] = *(const short8*)pa_hi;
            al[s] = *(const short8*)pa_lo;
            bh[s] = *(const short8*)(pb_hi + (size_t)g * 512);
            bl[s] = *(const short8*)(pb_lo + (size_t)g * 512);
        }
    }
    #pragma unroll
    for (int i = 0; i < 16; ++i) acc0[i] += acc1[i] + acc2[i];

    {   // dump 32x32 frags to Gt[64][65]
        const int col = wc * 32 + (lane & 31);
        const int rbase = wr * 32 + 4 * (lane >> 5);
        #pragma unroll
        for (int r = 0; r < 16; ++r)
            Gt[(rbase + (r & 3) + 8 * (r >> 2)) * 65 + col] = acc0[r];
    }
    __syncthreads();

    // cell update: thread -> (b = bi*64 + tid>>2, 4 consecutive j); c in VGPRs
    {
        const int bl2 = tid >> 2, jq = tid & 3;
        const int b = bi * 64 + bl2;
        const int j0 = ji * 16 + jq * 4;
        float hn4[4];
        u64 phi = 0, plo = 0;
        #pragma unroll
        for (int e = 0; e < 4; ++e) {
            const int jj = jq * 4 + e;
            const float gi = Gt[bl2 * 65 + jj]      + bias[j0 + e];
            const float gf = Gt[bl2 * 65 + 16 + jj] + bias[512 + j0 + e];
            const float gg = Gt[bl2 * 65 + 32 + jj] + bias[1024 + j0 + e];
            const float go = Gt[bl2 * 65 + 48 + jj] + bias[1536 + j0 + e];
            const float si = 1.f / (1.f + __expf(-gi));
            const float sf = 1.f / (1.f + __expf(-gf));
            const float so = 1.f / (1.f + __expf(-go));
            const float cn = sf * c4[e] + si * tanhf(gg);
            const float hn = so * tanhf(cn);
            c4[e] = cn; hn4[e] = hn;
            u16 hi, lo; split_bf(hn, hi, lo);
            phi |= (u64)hi << (16 * e);
            plo |= (u64)lo << (16 * e);
        }
        const int rb = b >> 5, gran = j0 >> 4;
        const int fl = ((j0 >> 3) & 1) * 32 + (b & 31);
        const size_t fo = (((size_t)rb * 32 + gran) * 64 + fl) * 8 + (j0 & 7);
        ast64(hout_hi + fo, phi);
        ast64(hout_lo + fo, plo);
        const size_t co = (size_t)b * Hz + j0;
        if (slot >= 0) {
            float* bp = buf + ((size_t)b * TSz + slot) * Hz + j0;
            ast64f(bp, hn4[0], hn4[1]);
            ast64f(bp + 2, hn4[2], hn4[3]);
        } else {
            float* hp = h_f32 + co;
            ast64f(hp, hn4[0], hn4[1]);
            ast64f(hp + 2, hn4[2], hn4[3]);
        }
    }
}

// ---------------- attention phase: 2 batches per block (normal cached reads) ----------------
__device__ __forceinline__ void attn_phase(const float* __restrict__ h_f32,
                                           float* __restrict__ buf,
                                           u16* __restrict__ ctx_hi, u16* __restrict__ ctx_lo,
                                           int base, float* lds, int bid, int tid) {
    float* sh = lds + (tid >> 7) * 544;
    float* sa = sh + 512;
    const int b = bid * 2 + (tid >> 7);
    const int t7 = tid & 127;
    for (int i = t7; i < 512; i += 128) sh[i] = h_f32[(size_t)b * Hz + i];
    __syncthreads();
    {   // 32 scores, 4 lanes each
        const int s = t7 >> 2, l4 = t7 & 3;
        const float* br = buf + ((size_t)b * TSz + ((base + s) & 31)) * Hz;
        float p = 0.f;
        #pragma unroll 16
        for (int j = l4; j < 512; j += 4) p = fmaf(sh[j], br[j], p);
        p += __shfl_xor(p, 1); p += __shfl_xor(p, 2);
        if (l4 == 0) sa[s] = p;
    }
    __syncthreads();
    if (t7 < 32) {   // softmax over 32
        const float v = sa[t7];
        float m = v;
        #pragma unroll
        for (int d = 1; d < 32; d <<= 1) m = fmaxf(m, __shfl_xor(m, d));
        const float e = __expf(v - m);
        float ss = e;
        #pragma unroll
        for (int d = 1; d < 32; d <<= 1) ss += __shfl_xor(ss, d);
        sa[t7] = e / ss;
    }
    __syncthreads();
    {   // ctx: thread t7 owns 4 consecutive j -> packed sc1 fragment store
        const int j0 = t7 * 4;
        float a4[4] = {0.f, 0.f, 0.f, 0.f};
        #pragma unroll
        for (int s2 = 0; s2 < TSz; ++s2) {
            const float w = sa[s2];
            const float* bp = buf + ((size_t)b * TSz + ((base + s2) & 31)) * Hz + j0;
            const float4 v4 = *(const float4*)bp;
            a4[0] = fmaf(w, v4.x, a4[0]);
            a4[1] = fmaf(w, v4.y, a4[1]);
            a4[2] = fmaf(w, v4.z, a4[2]);
            a4[3] = fmaf(w, v4.w, a4[3]);
        }
        u64 phi = 0, plo = 0;
        #pragma unroll
        for (int e = 0; e < 4; ++e) {
            u16 hi, lo; split_bf(a4[e], hi, lo);
            phi |= (u64)hi << (16 * e);
            plo |= (u64)lo << (16 * e);
        }
        const int rb = b >> 5, gran = j0 >> 4;
        const int fl = ((j0 >> 3) & 1) * 32 + (b & 31);
        const size_t fo = (((size_t)rb * 32 + gran) * 64 + fl) * 8 + (j0 & 7);
        ast64(ctx_hi + fo, phi);
        ast64(ctx_lo + fo, plo);
    }
    __syncthreads();
    #pragma unroll
    for (int pass = 0; pass < 2; ++pass) {   // append h_t to slot `base` (sc1)
        const int i = pass * 256 + t7 * 2;
        ast64f(buf + ((size_t)b * TSz + base) * Hz + i, sh[i], sh[i + 1]);
    }
}

// ---------------- MLP + partial out phase ----------------
__device__ __forceinline__ void mlp_phase(
    const u16* __restrict__ ctx_hi, const u16* __restrict__ ctx_lo,
    const u16* __restrict__ h_hi,   const u16* __restrict__ h_lo,
    const u16* __restrict__ w1_hi,  const u16* __restrict__ w1_lo,
    const float* __restrict__ b1, const float* __restrict__ W2,
    float* __restrict__ part_p, float* lds, int bid, int tid)
{
    const int lane = tid & 63, w = tid >> 6;
    const int ni = bid & 15, bi2 = bid >> 4;

    floatx16 acc0, acc1, acc2;
    #pragma unroll
    for (int i = 0; i < 16; ++i) { acc0[i] = 0.f; acc1[i] = 0.f; acc2[i] = 0.f; }

    short8 ah[PF], al[PF], bh[PF], bl[PF];

    #pragma unroll
    for (int gg = 0; gg < 16 + PF; ++gg) {
        if (gg >= PF) {
            const int s = (gg - PF) & (PF - 1);
            acc0 = __builtin_amdgcn_mfma_f32_32x32x16_bf16(ah[s], bh[s], acc0, 0, 0, 0);
            acc1 = __builtin_amdgcn_mfma_f32_32x32x16_bf16(ah[s], bl[s], acc1, 0, 0, 0);
            acc2 = __builtin_amdgcn_mfma_f32_32x32x16_bf16(al[s], bh[s], acc2, 0, 0, 0);
        }
        if (gg < 16) {
            const int s = gg & (PF - 1);
            const int g = w * 16 + gg;   // wave-split K
            const u16* pa_hi;
            const u16* pa_lo;
            if (g < 32) {
                const size_t off = (((size_t)bi2 * 32 + g) * 64 + lane) * 8;
                pa_hi = ctx_hi + off; pa_lo = ctx_lo + off;
            } else {
                const size_t off = (((size_t)bi2 * 32 + (g - 32)) * 64 + lane) * 8;
                pa_hi = h_hi + off; pa_lo = h_lo + off;
            }
            ah[s] = *(const short8*)pa_hi;
            al[s] = *(const short8*)pa_lo;
            const size_t boff = (((size_t)ni * 64 + g) * 64 + lane) * 8;
            bh[s] = *(const short8*)(w1_hi + boff);
            bl[s] = *(const short8*)(w1_lo + boff);
        }
    }
    #pragma unroll
    for (int i = 0; i < 16; ++i) acc0[i] += acc1[i] + acc2[i];

    {   // per-wave 32x32 partial -> lds[w][row][col]
        const int col = lane & 31;
        const int rb4 = 4 * (lane >> 5);
        #pragma unroll
        for (int r = 0; r < 16; ++r)
            lds[w * 1024 + (rb4 + (r & 3) + 8 * (r >> 2)) * 32 + col] = acc0[r];
    }
    __syncthreads();

    // reduce 4 wave-partials + bias, tanh, dot with W2 slice -> part_p (sc1)
    const int row = tid >> 3, l8 = tid & 7;
    float a = 0.f;
    #pragma unroll
    for (int jj = 0; jj < 4; ++jj) {
        const int col = l8 * 4 + jj;
        const int ncol = ni * 32 + col;
        const float pre = lds[row * 32 + col] + lds[1024 + row * 32 + col]
                        + lds[2048 + row * 32 + col] + lds[3072 + row * 32 + col] + b1[ncol];
        a = fmaf(tanhf(pre), W2[ncol], a);
    }
    a += __shfl_xor(a, 1); a += __shfl_xor(a, 2); a += __shfl_xor(a, 4);
    if (l8 == 0) astf(&part_p[ni * 512 + bi2 * 32 + row], a);
}

__device__ __forceinline__ void y_reduce(const float* __restrict__ part_p,
                                         const float* __restrict__ b2,
                                         float* __restrict__ y, int s, int bid, int tid) {
    if (tid < 2) {
        const int b = bid * 2 + tid;
        float a = b2[0];
        #pragma unroll
        for (int ni = 0; ni < 16; ++ni) a += part_p[ni * 512 + b];
        astf(&y[(size_t)b * PLz + s], a);   // sc1: survives later buffer_inv
    }
}

// ---------------- the persistent kernel ----------------
struct KParams {
    const u16 *xf_hi, *xf_lo, *wf_hi, *wf_lo, *wcf_hi, *wcf_lo, *w1f_hi, *w1f_lo;
    const float *b_l, *b_c, *b1, *W2, *b2;
    float *h_f32, *buf, *part_p, *y;
    u16 *hfa_hi, *hfa_lo, *hfb_hi, *hfb_lo, *ctx_hi, *ctx_lo;
    unsigned *sync;
};

__global__ __launch_bounds__(256) void k_persist(KParams p) {
    __shared__ float lds[4352];
    const int bid = blockIdx.x;
    const int tid = threadIdx.x;
    unsigned gen = 1;
    float c4[4] = {0.f, 0.f, 0.f, 0.f};   // persistent cell state (block-private mapping)

    // encoder: 128 steps
    for (int t = 0; t < Tz; ++t) {
        const u16* in_hi = (t & 1) ? p.hfb_hi : p.hfa_hi;
        const u16* in_lo = (t & 1) ? p.hfb_lo : p.hfa_lo;
        u16* out_hi = (t & 1) ? p.hfa_hi : p.hfb_hi;
        u16* out_lo = (t & 1) ? p.hfa_lo : p.hfb_lo;
        gates_phase<36, 4>(p.xf_hi, p.xf_lo, t, p.wf_hi, p.wf_lo, in_hi, in_lo,
                           p.b_l, c4, nullptr, out_hi, out_lo, p.buf, t & 31,
                           lds, bid, tid);
        gsync(p.sync, gen++, bid);
    }
    // decoder: 32 iterations (gates | attn | mlp+out)
    for (int s = 0; s < PLz; ++s) {
        if (s > 0) y_reduce(p.part_p, p.b2, p.y, s - 1, bid, tid);
        const u16* in_hi = (s & 1) ? p.hfb_hi : p.hfa_hi;
        const u16* in_lo = (s & 1) ? p.hfb_lo : p.hfa_lo;
        u16* out_hi = (s & 1) ? p.hfa_hi : p.hfb_hi;
        u16* out_lo = (s & 1) ? p.hfa_lo : p.hfb_lo;
        gates_phase<32, 0>(nullptr, nullptr, 0, p.wcf_hi, p.wcf_lo, in_hi, in_lo,
                           p.b_c, c4, p.h_f32, out_hi, out_lo, nullptr, -1,
                           lds, bid, tid);
        gsync(p.sync, gen++, bid);
        attn_phase(p.h_f32, p.buf, p.ctx_hi, p.ctx_lo, s & 31, lds, bid, tid);
        gsync(p.sync, gen++, bid);
        mlp_phase(p.ctx_hi, p.ctx_lo, out_hi, out_lo, p.w1f_hi, p.w1f_lo,
                  p.b1, p.W2, p.part_p, lds, bid, tid);
        gsync(p.sync, gen++, bid);
    }
    y_reduce(p.part_p, p.b2, p.y, PLz - 1, bid, tid);
}

extern "C" void kernel_launch(void* const* d_in, const int* in_sizes, int n_in,
                              void* d_out, int out_size, void* d_ws, size_t ws_size,
                              hipStream_t stream) {
    (void)in_sizes; (void)n_in; (void)out_size; (void)ws_size;
    const float* x     = (const float*)d_in[0];
    const float* W_ih  = (const float*)d_in[1];
    const float* W_hh  = (const float*)d_in[2];
    const float* b_l   = (const float*)d_in[3];
    const float* Wc_ih = (const float*)d_in[4];
    const float* Wc_hh = (const float*)d_in[5];
    const float* b_c   = (const float*)d_in[6];
    const float* W1    = (const float*)d_in[7];
    const float* b1    = (const float*)d_in[8];
    const float* W2    = (const float*)d_in[9];
    const float* b2    = (const float*)d_in[10];
    float* y = (float*)d_out;

    float* w = (float*)d_ws;
    float* h_f32  = w + BH;                     // BH
    float* buf    = w + 2 * (size_t)BH;         // 32*BH
    float* part_p = w + 34 * (size_t)BH;        // 8192
    unsigned* sync = (unsigned*)(w + 34 * (size_t)BH + 8192);   // 8192 u32
    u16* us = (u16*)(w + 34 * (size_t)BH + 8192 + 8192);
    u16* hfa_hi = us;  us += BH;
    u16* hfa_lo = us;  us += BH;
    u16* hfb_hi = us;  us += BH;
    u16* hfb_lo = us;  us += BH;
    u16* ctx_hi = us;  us += BH;
    u16* ctx_lo = us;  us += BH;
    u16* xf_hi = us;   us += 4194304;
    u16* xf_lo = us;   us += 4194304;
    u16* wf_hi = us;   us += 1179648;
    u16* wf_lo = us;   us += 1179648;
    u16* wcf_hi = us;  us += 1048576;
    u16* wcf_lo = us;  us += 1048576;
    u16* w1f_hi = us;  us += 524288;
    u16* w1f_lo = us;  us += 524288;

    k_init     <<<1024, 256, 0, stream>>>(hfa_hi, hfa_lo, sync);
    k_prep_wenc<<<576,  256, 0, stream>>>(W_ih, W_hh, wf_hi, wf_lo);
    k_prep_wc  <<<512,  256, 0, stream>>>(Wc_ih, Wc_hh, wcf_hi, wcf_lo);
    k_prep_w1  <<<256,  256, 0, stream>>>(W1, w1f_hi, w1f_lo);
    k_prep_x   <<<2048, 256, 0, stream>>>(x, xf_hi, xf_lo);

    KParams prm;
    prm.xf_hi = xf_hi;   prm.xf_lo = xf_lo;
    prm.wf_hi = wf_hi;   prm.wf_lo = wf_lo;
    prm.wcf_hi = wcf_hi; prm.wcf_lo = wcf_lo;
    prm.w1f_hi = w1f_hi; prm.w1f_lo = w1f_lo;
    prm.b_l = b_l; prm.b_c = b_c; prm.b1 = b1; prm.W2 = W2; prm.b2 = b2;
    prm.h_f32 = h_f32; prm.buf = buf; prm.part_p = part_p; prm.y = y;
    prm.hfa_hi = hfa_hi; prm.hfa_lo = hfa_lo;
    prm.hfb_hi = hfb_hi; prm.hfb_lo = hfb_lo;
    prm.ctx_hi = ctx_hi; prm.ctx_lo = ctx_lo;
    prm.sync = sync;

    k_persist<<<dim3(NBLK), dim3(256), 0, stream>>>(prm);
}

// Round 9
// 3283.541 us; speedup vs baseline: 2.9544x; 1.2786x over previous
//
#include <hip/hip_runtime.h>
#include <hip/hip_bf16.h>
#include <math.h>

// Problem sizes
#define Bz   512
#define Tz   128
#define INz  64
#define Hz   512
#define TSz  32
#define PLz  32
#define BH   (Bz * Hz)          // 262144
#define NBLK 256
#define NTHR 512
#define PF   6

typedef unsigned short u16;
typedef unsigned long long u64;
typedef __attribute__((ext_vector_type(8)))  short short8;
typedef __attribute__((ext_vector_type(16))) float floatx16;

static __device__ __forceinline__ void split_bf(float w, u16& hi, u16& lo) {
    __hip_bfloat16 h = __float2bfloat16(w);
    hi = *reinterpret_cast<u16*>(&h);
    float r = w - __bfloat162float(h);
    __hip_bfloat16 l = __float2bfloat16(r);
    lo = *reinterpret_cast<u16*>(&l);
}

// ---- sc1 (coherence-point) helpers: relaxed agent-scope atomics ----
union U64x2 { u64 q[2]; short8 v; };
union F2U { u64 q; float f[2]; };
union FU  { unsigned u; float f; };

static __device__ __forceinline__ short8 ald16(const u16* p) {
    U64x2 u;
    u.q[0] = __hip_atomic_load((const u64*)p,     __ATOMIC_RELAXED, __HIP_MEMORY_SCOPE_AGENT);
    u.q[1] = __hip_atomic_load((const u64*)p + 1, __ATOMIC_RELAXED, __HIP_MEMORY_SCOPE_AGENT);
    return u.v;
}
static __device__ __forceinline__ float aldf(const float* p) {
    FU c; c.u = __hip_atomic_load((const unsigned*)p, __ATOMIC_RELAXED, __HIP_MEMORY_SCOPE_AGENT);
    return c.f;
}
static __device__ __forceinline__ void ast64f(float* p, float a, float b) {
    F2U u; u.f[0] = a; u.f[1] = b;
    __hip_atomic_store((u64*)p, u.q, __ATOMIC_RELAXED, __HIP_MEMORY_SCOPE_AGENT);
}
static __device__ __forceinline__ void astf(float* p, float v) {
    FU c; c.f = v;
    __hip_atomic_store((unsigned*)p, c.u, __ATOMIC_RELAXED, __HIP_MEMORY_SCOPE_AGENT);
}
static __device__ __forceinline__ unsigned aldu(const unsigned* p) {
    return __hip_atomic_load(p, __ATOMIC_RELAXED, __HIP_MEMORY_SCOPE_AGENT);
}
static __device__ __forceinline__ void astu(unsigned* p, unsigned v) {
    __hip_atomic_store(p, v, __ATOMIC_RELAXED, __HIP_MEMORY_SCOPE_AGENT);
}
static __device__ __forceinline__ void astu16x2(u16* p, unsigned v) {
    __hip_atomic_store((unsigned*)p, v, __ATOMIC_RELAXED, __HIP_MEMORY_SCOPE_AGENT);
}

// ---------------- init: zero initial h fragments + sync area ----------------
__global__ __launch_bounds__(256) void k_init(u16* __restrict__ hf_hi,
                                              u16* __restrict__ hf_lo,
                                              unsigned* __restrict__ sync) {
    const int i = blockIdx.x * 256 + threadIdx.x;
    if (i < BH) { hf_hi[i] = 0; hf_lo[i] = 0; }
    if (i < 8192) sync[i] = 0;
}

// ---------------- prep kernels (unchanged, verified) ----------------
__global__ __launch_bounds__(256) void k_prep_wenc(const float* __restrict__ W_ih,
                                                   const float* __restrict__ W_hh,
                                                   u16* __restrict__ wf_hi,
                                                   u16* __restrict__ wf_lo) {
    const int idx = blockIdx.x * 256 + threadIdx.x;
    const int lane = idx & 63;
    const int g = (idx >> 6) % 36;
    const int cb = idx / (36 * 64);
    const int C = cb * 32 + (lane & 31);
    const int gate = ((C >> 4) & 3) * 512 + (C >> 6) * 16 + (C & 15);
    const int kh = lane >> 5;
    const size_t base = (size_t)idx * 8;
    #pragma unroll
    for (int e = 0; e < 8; ++e) {
        const int k = g * 16 + kh * 8 + e;
        const float w = (k < 64) ? W_ih[(size_t)gate * 64 + k]
                                 : W_hh[(size_t)gate * 512 + (k - 64)];
        u16 hi, lo; split_bf(w, hi, lo);
        wf_hi[base + e] = hi; wf_lo[base + e] = lo;
    }
}

__global__ __launch_bounds__(256) void k_prep_wc(const float* __restrict__ Wc_ih,
                                                 const float* __restrict__ Wc_hh,
                                                 u16* __restrict__ wf_hi,
                                                 u16* __restrict__ wf_lo) {
    const int idx = blockIdx.x * 256 + threadIdx.x;
    const int lane = idx & 63;
    const int cb = idx / (32 * 64);
    const int g = (idx >> 6) % 32;
    const int C = cb * 32 + (lane & 31);
    const int gate = ((C >> 4) & 3) * 512 + (C >> 6) * 16 + (C & 15);
    const int kh = lane >> 5;
    const size_t base = (size_t)idx * 8;
    #pragma unroll
    for (int e = 0; e < 8; ++e) {
        const int k = g * 16 + kh * 8 + e;
        const float w = Wc_ih[(size_t)gate * 512 + k] + Wc_hh[(size_t)gate * 512 + k];
        u16 hi, lo; split_bf(w, hi, lo);
        wf_hi[base + e] = hi; wf_lo[base + e] = lo;
    }
}

__global__ __launch_bounds__(256) void k_prep_w1(const float* __restrict__ W1,
                                                 u16* __restrict__ wf_hi,
                                                 u16* __restrict__ wf_lo) {
    const int idx = blockIdx.x * 256 + threadIdx.x;
    const int lane = idx & 63;
    const int cb = idx / (64 * 64);
    const int g = (idx >> 6) % 64;
    const int n = cb * 32 + (lane & 31);
    const int kh = lane >> 5;
    const size_t base = (size_t)idx * 8;
    #pragma unroll
    for (int e = 0; e < 8; ++e) {
        const int k = g * 16 + kh * 8 + e;
        const float w = W1[(size_t)n * 1024 + k];
        u16 hi, lo; split_bf(w, hi, lo);
        wf_hi[base + e] = hi; wf_lo[base + e] = lo;
    }
}

__global__ __launch_bounds__(256) void k_prep_x(const float* __restrict__ x,
                                                u16* __restrict__ xf_hi,
                                                u16* __restrict__ xf_lo) {
    const int idx = blockIdx.x * 256 + threadIdx.x;
    const int lane = idx & 63;
    const int g = (idx >> 6) & 3;
    const int rb = (idx >> 8) & 15;
    const int t = idx >> 12;
    const int b = rb * 32 + (lane & 31);
    const int kh = lane >> 5;
    const size_t base = (size_t)idx * 8;
    #pragma unroll
    for (int e = 0; e < 8; ++e) {
        const int i = g * 16 + kh * 8 + e;
        const float w = x[((size_t)b * Tz + t) * INz + i];
        u16 hi, lo; split_bf(w, hi, lo);
        xf_hi[base + e] = hi; xf_lo[base + e] = lo;
    }
}

// ---------------- grid barrier: slot-arrival + scan + group release; NO FENCE ----------------
// sc1 data stores are drained by __syncthreads (vmcnt0) before the arrival store;
// all cross-block data travels sc1 or write-once addresses, so no invalidate is needed.
static __device__ __forceinline__ void gsync(unsigned* sync, unsigned target, int bid) {
    __syncthreads();
    const int tid = threadIdx.x;
    unsigned* arr  = sync + 64;
    unsigned* grel = sync + 64 + 4096;
    if (bid == 0) {
        if (tid < 64) {
            if (tid == 0) astu(&arr[0], target);
            bool done = false;
            while (!done) {
                unsigned mn = 0xffffffffu;
                #pragma unroll
                for (int k = 0; k < 4; ++k) {
                    const unsigned v = aldu(&arr[(tid * 4 + k) * 16]);
                    mn = v < mn ? v : mn;
                }
                done = (bool)__all((int)(mn >= target));
                if (!done) __builtin_amdgcn_s_sleep(1);
            }
            if (tid < 16) astu(&grel[tid * 16], target);
        }
    } else {
        if (tid == 0) {
            astu(&arr[bid * 16], target);
            while (aldu(&grel[(bid >> 4) * 16]) < target)
                __builtin_amdgcn_s_sleep(1);
        }
    }
    __syncthreads();
}

// ---------------- gates + cell phase: 8 waves, K-split (kh) ----------------
// Weights/x: normal cached (L2-warm forever, no invalidation). h frags: sc1.
template<int NG, int GX>
__device__ __forceinline__ void gates_phase(
    const u16* __restrict__ xf_hi, const u16* __restrict__ xf_lo, int t,
    const u16* __restrict__ wf_hi, const u16* __restrict__ wf_lo,
    const u16* __restrict__ hin_hi, const u16* __restrict__ hin_lo,
    const float* __restrict__ bias,
    float (&c2)[2], float* __restrict__ h_f32,
    u16* __restrict__ hout_hi, u16* __restrict__ hout_lo,
    float* __restrict__ buf_enc, int slot,
    float* Gt, int bid, int tid)
{
    const int lane = tid & 63, wid = tid >> 6;
    const int wc = wid & 1, wr = (wid >> 1) & 1, kh = wid >> 2;
    const int ji = bid & 31, bi = bid >> 5;
    const int rbIdx = bi * 2 + wr;
    const int cbIdx = ji * 2 + wc;
    constexpr int NGH = NG / 2;
    const int g0 = kh * NGH;

    floatx16 acc0, acc1, acc2;
    #pragma unroll
    for (int i = 0; i < 16; ++i) { acc0[i] = 0.f; acc1[i] = 0.f; acc2[i] = 0.f; }

    const u16* pbh = wf_hi + ((size_t)cbIdx * NG) * 512 + lane * 8;
    const u16* pbl = wf_lo + ((size_t)cbIdx * NG) * 512 + lane * 8;

    short8 ah[PF], al[PF], bh[PF], bl[PF];

    #pragma unroll
    for (int i = 0; i < NGH + PF; ++i) {
        if (i >= PF) {   // consume granule i-PF
            const int s = (i - PF) % PF;
            acc0 = __builtin_amdgcn_mfma_f32_32x32x16_bf16(ah[s], bh[s], acc0, 0, 0, 0);
            acc1 = __builtin_amdgcn_mfma_f32_32x32x16_bf16(ah[s], bl[s], acc1, 0, 0, 0);
            acc2 = __builtin_amdgcn_mfma_f32_32x32x16_bf16(al[s], bh[s], acc2, 0, 0, 0);
        }
        if (i < NGH) {   // refill slot with granule g0+i
            const int s = i % PF;
            const int g = g0 + i;
            if (g < GX) {   // x part: cached
                const size_t off = ((((size_t)t * 16 + rbIdx) * 4 + g) * 64 + lane) * 8;
                ah[s] = *(const short8*)(xf_hi + off);
                al[s] = *(const short8*)(xf_lo + off);
            } else {        // h part: sc1 (always coherent)
                const size_t off = (((size_t)rbIdx * 32 + (g - GX)) * 64 + lane) * 8;
                ah[s] = ald16(hin_hi + off);
                al[s] = ald16(hin_lo + off);
            }
            bh[s] = *(const short8*)(pbh + (size_t)g * 512);
            bl[s] = *(const short8*)(pbl + (size_t)g * 512);
        }
    }
    #pragma unroll
    for (int i = 0; i < 16; ++i) acc0[i] += acc1[i] + acc2[i];

    {   // dump 32x32 frags to Gt[kh][64][65]
        const int col = wc * 32 + (lane & 31);
        const int rbase = wr * 32 + 4 * (lane >> 5);
        float* G = Gt + kh * 4160;
        #pragma unroll
        for (int r = 0; r < 16; ++r)
            G[(rbase + (r & 3) + 8 * (r >> 2)) * 65 + col] = acc0[r];
    }
    __syncthreads();

    // cell update: thread -> (b = bi*64 + tid>>3, 2 consecutive j); c in VGPRs
    {
        const int bl2 = tid >> 3, jq = tid & 7;
        const int b = bi * 64 + bl2;
        const int j0 = ji * 16 + jq * 2;
        float hn2[2];
        unsigned phi = 0, plo = 0;
        #pragma unroll
        for (int e = 0; e < 2; ++e) {
            const int jj = jq * 2 + e;
            const float gi = Gt[bl2 * 65 + jj]      + Gt[4160 + bl2 * 65 + jj]      + bias[j0 + e];
            const float gf = Gt[bl2 * 65 + 16 + jj] + Gt[4160 + bl2 * 65 + 16 + jj] + bias[512 + j0 + e];
            const float gg = Gt[bl2 * 65 + 32 + jj] + Gt[4160 + bl2 * 65 + 32 + jj] + bias[1024 + j0 + e];
            const float go = Gt[bl2 * 65 + 48 + jj] + Gt[4160 + bl2 * 65 + 48 + jj] + bias[1536 + j0 + e];
            const float si = 1.f / (1.f + __expf(-gi));
            const float sf = 1.f / (1.f + __expf(-gf));
            const float so = 1.f / (1.f + __expf(-go));
            const float cn = sf * c2[e] + si * tanhf(gg);
            const float hn = so * tanhf(cn);
            c2[e] = cn; hn2[e] = hn;
            u16 hi, lo; split_bf(hn, hi, lo);
            phi |= (unsigned)hi << (16 * e);
            plo |= (unsigned)lo << (16 * e);
        }
        const int rb = b >> 5, gran = j0 >> 4;
        const int fl = ((j0 >> 3) & 1) * 32 + (b & 31);
        const size_t fo = (((size_t)rb * 32 + gran) * 64 + fl) * 8 + (j0 & 7);
        astu16x2(hout_hi + fo, phi);
        astu16x2(hout_lo + fo, plo);
        if (slot >= 0)
            ast64f(buf_enc + ((size_t)b * TSz + slot) * Hz + j0, hn2[0], hn2[1]);
        if (h_f32 != nullptr)
            ast64f(h_f32 + (size_t)b * Hz + j0, hn2[0], hn2[1]);
    }
}

// ---------------- attention: 2 batches/block; ring via write-once cached reads ----------------
__device__ __forceinline__ void attn_phase(const float* __restrict__ h_f32,
                                           const float* __restrict__ buf_enc,
                                           float* __restrict__ buf_dec,
                                           u16* __restrict__ ctx_hi, u16* __restrict__ ctx_lo,
                                           int sd, float* lds, int bid, int tid) {
    const int grp = tid >> 8;
    const int t8 = tid & 255;
    const int b = bid * 2 + grp;
    float* sh = lds + grp * 544;
    float* sa = sh + 512;
    {   // stage h row via sc1 (h_f32 rewritten each step -> must bypass caches)
        const int i0 = t8 * 2;
        sh[i0]     = aldf(h_f32 + (size_t)b * Hz + i0);
        sh[i0 + 1] = aldf(h_f32 + (size_t)b * Hz + i0 + 1);
    }
    __syncthreads();
    {   // 32 scores x 8 lanes; ring reads cached (write-once addresses)
        const int w = t8 >> 3, l8 = t8 & 7;
        const float* v = (w < TSz - sd)
            ? buf_enc + ((size_t)b * TSz + (sd + w)) * Hz
            : buf_dec + (size_t)(w - TSz + sd) * BH + (size_t)b * Hz;
        float p = 0.f;
        for (int j = l8; j < Hz; j += 8) p = fmaf(sh[j], v[j], p);
        p += __shfl_xor(p, 1); p += __shfl_xor(p, 2); p += __shfl_xor(p, 4);
        if (l8 == 0) sa[w] = p;
    }
    __syncthreads();
    if (t8 < TSz) {   // softmax over 32 (lanes 0..31 of a wave in each group)
        const float v = sa[t8];
        float m = v;
        #pragma unroll
        for (int d = 1; d < 32; d <<= 1) m = fmaxf(m, __shfl_xor(m, d));
        const float e = __expf(v - m);
        float ss = e;
        #pragma unroll
        for (int d = 1; d < 32; d <<= 1) ss += __shfl_xor(ss, d);
        sa[t8] = e / ss;
    }
    __syncthreads();
    {   // ctx: 2 consecutive j per thread; cached ring reads; sc1 frag store
        const int j0 = t8 * 2;
        float a0 = 0.f, a1 = 0.f;
        for (int w2 = 0; w2 < TSz; ++w2) {
            const float* vp = (w2 < TSz - sd)
                ? buf_enc + ((size_t)b * TSz + (sd + w2)) * Hz + j0
                : buf_dec + (size_t)(w2 - TSz + sd) * BH + (size_t)b * Hz + j0;
            const float2 vv = *(const float2*)vp;
            a0 = fmaf(sa[w2], vv.x, a0);
            a1 = fmaf(sa[w2], vv.y, a1);
        }
        u16 h0, l0, h1, l1;
        split_bf(a0, h0, l0); split_bf(a1, h1, l1);
        const int rb = b >> 5, gran = j0 >> 4;
        const int fl = ((j0 >> 3) & 1) * 32 + (b & 31);
        const size_t fo = (((size_t)rb * 32 + gran) * 64 + fl) * 8 + (j0 & 7);
        astu16x2(ctx_hi + fo, (unsigned)h0 | ((unsigned)h1 << 16));
        astu16x2(ctx_lo + fo, (unsigned)l0 | ((unsigned)l1 << 16));
    }
    {   // append h_sd to fresh buffer buf_dec[sd] (sc1)
        const int i0 = t8 * 2;
        ast64f(buf_dec + (size_t)sd * BH + (size_t)b * Hz + i0, sh[i0], sh[i0 + 1]);
    }
}

// ---------------- MLP + partial out: 8-wave K-split ----------------
__device__ __forceinline__ void mlp_phase(
    const u16* __restrict__ ctx_hi, const u16* __restrict__ ctx_lo,
    const u16* __restrict__ h_hi,   const u16* __restrict__ h_lo,
    const u16* __restrict__ w1_hi,  const u16* __restrict__ w1_lo,
    const float* __restrict__ b1, const float* __restrict__ W2,
    float* __restrict__ part_p, float* lds, int bid, int tid)
{
    const int lane = tid & 63, w = tid >> 6;
    const int ni = bid & 15, bi2 = bid >> 4;

    floatx16 acc0, acc1, acc2;
    #pragma unroll
    for (int i = 0; i < 16; ++i) { acc0[i] = 0.f; acc1[i] = 0.f; acc2[i] = 0.f; }

    short8 ah[4], al[4], bh[4], bl[4];

    #pragma unroll
    for (int i = 0; i < 8 + 4; ++i) {
        if (i >= 4) {
            const int s = (i - 4) & 3;
            acc0 = __builtin_amdgcn_mfma_f32_32x32x16_bf16(ah[s], bh[s], acc0, 0, 0, 0);
            acc1 = __builtin_amdgcn_mfma_f32_32x32x16_bf16(ah[s], bl[s], acc1, 0, 0, 0);
            acc2 = __builtin_amdgcn_mfma_f32_32x32x16_bf16(al[s], bh[s], acc2, 0, 0, 0);
        }
        if (i < 8) {
            const int s = i & 3;
            const int g = w * 8 + i;   // [0,64): wave-split K
            if (g < 32) {
                const size_t off = (((size_t)bi2 * 32 + g) * 64 + lane) * 8;
                ah[s] = ald16(ctx_hi + off);
                al[s] = ald16(ctx_lo + off);
            } else {
                const size_t off = (((size_t)bi2 * 32 + (g - 32)) * 64 + lane) * 8;
                ah[s] = ald16(h_hi + off);
                al[s] = ald16(h_lo + off);
            }
            const size_t boff = (((size_t)ni * 64 + g) * 64 + lane) * 8;
            bh[s] = *(const short8*)(w1_hi + boff);   // cached, warm
            bl[s] = *(const short8*)(w1_lo + boff);
        }
    }
    #pragma unroll
    for (int i = 0; i < 16; ++i) acc0[i] += acc1[i] + acc2[i];

    {   // per-wave 32x32 partial -> lds[w][row][col]
        const int col = lane & 31;
        const int rb4 = 4 * (lane >> 5);
        #pragma unroll
        for (int r = 0; r < 16; ++r)
            lds[w * 1024 + (rb4 + (r & 3) + 8 * (r >> 2)) * 32 + col] = acc0[r];
    }
    __syncthreads();

    // reduce 8 wave-partials + bias, tanh, dot with W2 slice -> part_p (sc1)
    const int row = tid >> 4, l16 = tid & 15;
    float a = 0.f;
    #pragma unroll
    for (int jj = 0; jj < 2; ++jj) {
        const int col = l16 * 2 + jj;
        const int ncol = ni * 32 + col;
        float pre = b1[ncol];
        #pragma unroll
        for (int ww = 0; ww < 8; ++ww) pre += lds[ww * 1024 + row * 32 + col];
        a = fmaf(tanhf(pre), W2[ncol], a);
    }
    a += __shfl_xor(a, 1); a += __shfl_xor(a, 2);
    a += __shfl_xor(a, 4); a += __shfl_xor(a, 8);
    if (l16 == 0) astf(&part_p[ni * 512 + bi2 * 32 + row], a);
}

__device__ __forceinline__ void y_reduce(const float* __restrict__ part_p,
                                         const float* __restrict__ b2,
                                         float* __restrict__ y, int s, int bid, int tid) {
    if (tid < 2) {
        const int b = bid * 2 + tid;
        float a = b2[0];
        #pragma unroll
        for (int ni = 0; ni < 16; ++ni) a += aldf(&part_p[ni * 512 + b]);
        astf(&y[(size_t)b * PLz + s], a);
    }
}

// ---------------- the persistent kernel ----------------
struct KParams {
    const u16 *xf_hi, *xf_lo, *wf_hi, *wf_lo, *wcf_hi, *wcf_lo, *w1f_hi, *w1f_lo;
    const float *b_l, *b_c, *b1, *W2, *b2;
    float *h_f32, *buf_enc, *buf_dec, *part_p, *y;
    u16 *hfa_hi, *hfa_lo, *hfb_hi, *hfb_lo, *ctx_hi, *ctx_lo;
    unsigned *sync;
};

__global__ __launch_bounds__(NTHR, 1) void k_persist(KParams p) {
    __shared__ float s_gt[2 * 64 * 65];   // 33 KB; aliased by attn (2*544) and mlp (8*1024)
    const int bid = blockIdx.x;
    const int tid = threadIdx.x;
    unsigned gen = 1;
    float c2[2] = {0.f, 0.f};   // persistent cell state

    // encoder: 128 steps; ring written only for t >= 96 (slot t-96, write-once)
    for (int t = 0; t < Tz; ++t) {
        const u16* in_hi = (t & 1) ? p.hfb_hi : p.hfa_hi;
        const u16* in_lo = (t & 1) ? p.hfb_lo : p.hfa_lo;
        u16* out_hi = (t & 1) ? p.hfa_hi : p.hfb_hi;
        u16* out_lo = (t & 1) ? p.hfa_lo : p.hfb_lo;
        gates_phase<36, 4>(p.xf_hi, p.xf_lo, t, p.wf_hi, p.wf_lo, in_hi, in_lo,
                           p.b_l, c2, nullptr, out_hi, out_lo,
                           p.buf_enc, t - 96, s_gt, bid, tid);
        gsync(p.sync, gen++, bid);
    }
    // decoder: 32 iterations (gates | attn | mlp)
    for (int sd = 0; sd < PLz; ++sd) {
        if (sd > 0) y_reduce(p.part_p, p.b2, p.y, sd - 1, bid, tid);
        const u16* in_hi = (sd & 1) ? p.hfb_hi : p.hfa_hi;
        const u16* in_lo = (sd & 1) ? p.hfb_lo : p.hfa_lo;
        u16* out_hi = (sd & 1) ? p.hfa_hi : p.hfb_hi;
        u16* out_lo = (sd & 1) ? p.hfa_lo : p.hfb_lo;
        gates_phase<32, 0>(nullptr, nullptr, 0, p.wcf_hi, p.wcf_lo, in_hi, in_lo,
                           p.b_c, c2, p.h_f32, out_hi, out_lo,
                           nullptr, -1, s_gt, bid, tid);
        gsync(p.sync, gen++, bid);
        attn_phase(p.h_f32, p.buf_enc, p.buf_dec, p.ctx_hi, p.ctx_lo, sd, s_gt, bid, tid);
        gsync(p.sync, gen++, bid);
        mlp_phase(p.ctx_hi, p.ctx_lo, out_hi, out_lo, p.w1f_hi, p.w1f_lo,
                  p.b1, p.W2, p.part_p, s_gt, bid, tid);
        gsync(p.sync, gen++, bid);
    }
    y_reduce(p.part_p, p.b2, p.y, PLz - 1, bid, tid);
}

extern "C" void kernel_launch(void* const* d_in, const int* in_sizes, int n_in,
                              void* d_out, int out_size, void* d_ws, size_t ws_size,
                              hipStream_t stream) {
    (void)in_sizes; (void)n_in; (void)out_size; (void)ws_size;
    const float* x     = (const float*)d_in[0];
    const float* W_ih  = (const float*)d_in[1];
    const float* W_hh  = (const float*)d_in[2];
    const float* b_l   = (const float*)d_in[3];
    const float* Wc_ih = (const float*)d_in[4];
    const float* Wc_hh = (const float*)d_in[5];
    const float* b_c   = (const float*)d_in[6];
    const float* W1    = (const float*)d_in[7];
    const float* b1    = (const float*)d_in[8];
    const float* W2    = (const float*)d_in[9];
    const float* b2    = (const float*)d_in[10];
    float* y = (float*)d_out;

    float* w = (float*)d_ws;
    float* h_f32   = w;                              // BH
    float* buf_enc = w + BH;                         // 32*BH
    float* buf_dec = w + 33 * (size_t)BH;            // 32*BH
    float* part_p  = w + 65 * (size_t)BH;            // 8192
    unsigned* sync = (unsigned*)(w + 65 * (size_t)BH + 8192);   // 8192 u32
    u16* us = (u16*)(w + 65 * (size_t)BH + 8192 + 8192);
    u16* hfa_hi = us;  us += BH;
    u16* hfa_lo = us;  us += BH;
    u16* hfb_hi = us;  us += BH;
    u16* hfb_lo = us;  us += BH;
    u16* ctx_hi = us;  us += BH;
    u16* ctx_lo = us;  us += BH;
    u16* xf_hi = us;   us += 4194304;
    u16* xf_lo = us;   us += 4194304;
    u16* wf_hi = us;   us += 1179648;
    u16* wf_lo = us;   us += 1179648;
    u16* wcf_hi = us;  us += 1048576;
    u16* wcf_lo = us;  us += 1048576;
    u16* w1f_hi = us;  us += 524288;
    u16* w1f_lo = us;  us += 524288;

    k_init     <<<1024, 256, 0, stream>>>(hfa_hi, hfa_lo, sync);
    k_prep_wenc<<<576,  256, 0, stream>>>(W_ih, W_hh, wf_hi, wf_lo);
    k_prep_wc  <<<512,  256, 0, stream>>>(Wc_ih, Wc_hh, wcf_hi, wcf_lo);
    k_prep_w1  <<<256,  256, 0, stream>>>(W1, w1f_hi, w1f_lo);
    k_prep_x   <<<2048, 256, 0, stream>>>(x, xf_hi, xf_lo);

    KParams prm;
    prm.xf_hi = xf_hi;   prm.xf_lo = xf_lo;
    prm.wf_hi = wf_hi;   prm.wf_lo = wf_lo;
    prm.wcf_hi = wcf_hi; prm.wcf_lo = wcf_lo;
    prm.w1f_hi = w1f_hi; prm.w1f_lo = w1f_lo;
    prm.b_l = b_l; prm.b_c = b_c; prm.b1 = b1; prm.W2 = W2; prm.b2 = b2;
    prm.h_f32 = h_f32; prm.buf_enc = buf_enc; prm.buf_dec = buf_dec;
    prm.part_p = part_p; prm.y = y;
    prm.hfa_hi = hfa_hi; prm.hfa_lo = hfa_lo;
    prm.hfb_hi = hfb_hi; prm.hfb_lo = hfb_lo;
    prm.ctx_hi = ctx_hi; prm.ctx_lo = ctx_lo;
    prm.sync = sync;

    k_persist<<<dim3(NBLK), dim3(NTHR), 0, stream>>>(prm);
}